// Round 6
// baseline (512.404 us; speedup 1.0000x reference)
//
#include <hip/hip_runtime.h>

typedef unsigned short u16;
typedef __attribute__((ext_vector_type(8))) short bf16x8;
typedef __attribute__((ext_vector_type(4))) float f32x4;

__device__ inline float bf2f(u16 h) {
    union { unsigned u; float f; } v; v.u = ((unsigned)h) << 16; return v.f;
}
__device__ inline u16 f2bf(float f) {
    union { float f; unsigned u; } v; v.f = f;
    unsigned r = v.u + 0x7fffu + ((v.u >> 16) & 1u);
    return (u16)(r >> 16);
}

__device__ inline void gl_lds16(const u16* g, u16* l) {
    __builtin_amdgcn_global_load_lds(
        (const __attribute__((address_space(1))) void*)g,
        (__attribute__((address_space(3))) void*)l, 16, 0, 0);
}

__device__ __forceinline__ void wgbar() {
    asm volatile("" ::: "memory");
    __builtin_amdgcn_s_barrier();
    asm volatile("" ::: "memory");
}
#define VMW(n) asm volatile("s_waitcnt vmcnt(" #n ")" ::: "memory")

// ---------------------------------------------------------------------------
// f32 -> bf16 elementwise convert, up to 4 arrays per launch.
// ---------------------------------------------------------------------------
__global__ __launch_bounds__(256) void cvt_bf16_k(
    const float* __restrict__ s0, u16* __restrict__ d0, long long n0,
    const float* __restrict__ s1, u16* __restrict__ d1, long long n1,
    const float* __restrict__ s2, u16* __restrict__ d2, long long n2,
    const float* __restrict__ s3, u16* __restrict__ d3, long long n3)
{
    int y = blockIdx.y;
    const float* s = (y == 0) ? s0 : (y == 1) ? s1 : (y == 2) ? s2 : s3;
    u16* d         = (y == 0) ? d0 : (y == 1) ? d1 : (y == 2) ? d2 : d3;
    long long n    = (y == 0) ? n0 : (y == 1) ? n1 : (y == 2) ? n2 : n3;
    for (long long i = (long long)blockIdx.x * 256 + threadIdx.x; i < n;
         i += (long long)gridDim.x * 256) {
        float4 v = ((const float4*)s)[i];
        union { u16 h[4]; unsigned long long u; } p;
        p.h[0] = f2bf(v.x); p.h[1] = f2bf(v.y);
        p.h[2] = f2bf(v.z); p.h[3] = f2bf(v.w);
        ((unsigned long long*)d)[i] = p.u;
    }
}

// ---------------------------------------------------------------------------
// 256x256 double-buffered GEMM: C[M,N] = (A[M,K] @ Bt[N,K]^T)*scale + bias
// BK=64. 512 thr = 8 waves (2M x 4N), wave tile 128x64, acc[8][4].
// LDS 128KB: 2 slots x (A[2 halves][128][64] + B[2 halves][128][64]) bf16,
// XOR-swizzled (col-group ^= row&7) with inverse-swizzled global source.
// Per wave: only its A-half (wm) and B-site (wn) are ever ds_read.
// 4 phases/tile: ph0 {A i0-3 ks0+ks1 + B ks0 reads | stage As0x2+Bn0 | bar |
// 16 MFMA i0-3 ks0 | bar}; ph1 {B ks1 reads | stage Bn1-3 | VMW(6) | bar |
// 16 MFMA i0-3 ks1 | bar}; ph2 {A i4-7 reads | stage A0s1 | bar | 16 MFMA
// i4-7 ks0 | bar}; ph3 {stage A1s1 | VMW(2) | bar | 16 MFMA i4-7 ks1 | bar}.
// Ledger: stage order/tile = [A0s0,A1s0,Bn0 | Bn1,Bn2,Bn3 | A0s1 | A1s1].
//   VMW(2)@ph3 of tile t confirms t+1's first 6 (= everything ph0/ph1 of
//   t+1 reads); VMW(6)@ph1 of t confirms t's own A?s1 (read in ph2-3).
//   Never vmcnt(0) mid-loop (only last tile's ph1).
// XCD-aware block swizzle (grid%8==0). NSPLIT: cols in 1024-wide segments.
// BIASROW: bias by output row. bofs_stride: per-batch B K-offset (PV).
// ---------------------------------------------------------------------------
#define STA_S(T, H, SI)                                                       \
    { const u16* g_ = Ag + (long long)((H) * 128 + (SI) * 64 + w * 8 + srow)  \
                      * K + (long long)(T) * 64 + scol;                       \
      gl_lds16(g_, &As[(T) & 1][H][(SI) * 4096 + w * 512]); }

#define STB_S(T, NQ)                                                          \
    { const u16* g_ = Bg + (long long)(bn0 + (NQ) * 64 + w * 8 + srow) * ldb  \
                      + (long long)(T) * 64 + scol;                           \
      gl_lds16(g_, &Bs[(T) & 1][(NQ) >> 1][((NQ) & 1) * 4096 + w * 512]); }

#define MMA16(AV, BV, I0)                                                     \
    __builtin_amdgcn_s_setprio(1);                                            \
    _Pragma("unroll")                                                         \
    for (int ii = 0; ii < 4; ii++)                                            \
        _Pragma("unroll")                                                     \
        for (int jj = 0; jj < 4; jj++)                                        \
            acc[(I0) + ii][jj] = __builtin_amdgcn_mfma_f32_16x16x32_bf16(     \
                AV[ii], BV[jj], acc[(I0) + ii][jj], 0, 0, 0);                 \
    __builtin_amdgcn_s_setprio(0);

template <int COUTF32, int BIASROW, int NSPLIT>
__global__ __launch_bounds__(512, 2) void gemm256(
    const u16* __restrict__ A, const u16* __restrict__ Bt,
    const float* __restrict__ bias0, const float* __restrict__ bias1,
    void* __restrict__ C0, void* __restrict__ C1,
    int M, int N, int K, int ldb, float scale,
    long long sAb, long long sBb, long long sCb, long long bofs_stride)
{
    __shared__ u16 As[2][2][8192];   // slot, M-half, [128][64]
    __shared__ u16 Bs[2][2][8192];   // slot, N-half, [128][64]

    // XCD-aware bijective block swizzle (requires total blocks % 8 == 0).
    int gx = gridDim.x, gy = gridDim.y;
    int n = gx * gy * gridDim.z;
    int flat = (blockIdx.z * gy + blockIdx.y) * gx + blockIdx.x;
    int L = (flat & 7) * (n >> 3) + (flat >> 3);
    int bz = L / (gx * gy);
    int rr = L - bz * gx * gy;
    int by = rr / gx, bx = rr - (rr / gx) * gx;

    int bm0 = bx * 256;
    int bn0 = by * 256;
    int b   = bz;
    int tid = threadIdx.x;
    int w = tid >> 6, l = tid & 63;
    int wm = w >> 2;             // A half (128 rows)
    int wn = w & 3;              // B site / N quarter (64 cols)
    int lane15 = l & 15, quad = l >> 4;
    int xr = (l & 7) << 3;       // read-side swizzle (elems); row&7 == l&7

    // staging lane geometry: 8 lanes/row, inverse-swizzled source col-group
    int srow = l >> 3;
    int scol = ((l & 7) ^ srow) * 8;

    const u16* Ag = A  + (long long)b * sAb + (long long)bm0 * K;
    const u16* Bg = Bt + (long long)b * sBb + (long long)(bm0 >> 11) * bofs_stride;

    f32x4 acc[8][4];
#pragma unroll
    for (int i = 0; i < 8; i++)
#pragma unroll
        for (int j = 0; j < 4; j++) acc[i][j] = (f32x4)(0.0f);

    int NT = K >> 6;

    // Prologue: tile0 all 8 sites; tile1 first 6; confirm tile0's first 6.
    STA_S(0, 0, 0); STA_S(0, 1, 0);
    STB_S(0, 0); STB_S(0, 1); STB_S(0, 2); STB_S(0, 3);
    STA_S(0, 0, 1); STA_S(0, 1, 1);
    STA_S(1, 0, 0); STA_S(1, 1, 0);
    STB_S(1, 0); STB_S(1, 1); STB_S(1, 2); STB_S(1, 3);
    VMW(8);
    wgbar();

    for (int t = 0; t < NT; ++t) {
        int T = t + 1;
        int s = t & 1;
        bool sf = (t > 0) && (T < NT);   // full-rate staging (3+3 in ph0/ph1)
        bool st = (T < NT);              // tail A-sites staging (ph2/ph3)
        const u16* Ah = &As[s][wm][0];
        const u16* Bh = &Bs[s][wn >> 1][0];
        int brow = (wn & 1) * 64;

        bf16x8 a0[4], a1[4], b0[4], b1[4];
        // ---- ph0: A i0-3 (ks0+ks1) + B ks0 reads; stage A0s0,A1s0,Bn0
#pragma unroll
        for (int ii = 0; ii < 4; ii++) {
            int r = ii * 16 + lane15;
            a0[ii] = *(const bf16x8*)&Ah[(r * 64 + quad * 8) ^ xr];
            a1[ii] = *(const bf16x8*)&Ah[(r * 64 + 32 + quad * 8) ^ xr];
        }
#pragma unroll
        for (int jj = 0; jj < 4; jj++) {
            int r = brow + jj * 16 + lane15;
            b0[jj] = *(const bf16x8*)&Bh[(r * 64 + quad * 8) ^ xr];
        }
        if (sf) { STA_S(T, 0, 0); STA_S(T, 1, 0); STB_S(T, 0); }
        wgbar();
        MMA16(a0, b0, 0);
        wgbar();

        // ---- ph1: B ks1 reads; stage Bn1-3; VMW(6) confirms own A?s1
#pragma unroll
        for (int jj = 0; jj < 4; jj++) {
            int r = brow + jj * 16 + lane15;
            b1[jj] = *(const bf16x8*)&Bh[(r * 64 + 32 + quad * 8) ^ xr];
        }
        if (sf) { STB_S(T, 1); STB_S(T, 2); STB_S(T, 3); }
        if (t == NT - 1) { VMW(0); } else { VMW(6); }
        wgbar();
        MMA16(a1, b1, 0);
        wgbar();

        // ---- ph2: A i4-7 (ks0+ks1) reads; stage A0s1
#pragma unroll
        for (int ii = 0; ii < 4; ii++) {
            int r = 64 + ii * 16 + lane15;
            a0[ii] = *(const bf16x8*)&Ah[(r * 64 + quad * 8) ^ xr];
            a1[ii] = *(const bf16x8*)&Ah[(r * 64 + 32 + quad * 8) ^ xr];
        }
        if (st) { STA_S(T, 0, 1); }
        wgbar();
        MMA16(a0, b0, 4);
        wgbar();

        // ---- ph3: stage A1s1; VMW(2) confirms next tile's first 6
        if (st) { STA_S(T, 1, 1); VMW(2); }
        wgbar();
        MMA16(a1, b1, 4);
        wgbar();
    }

    // Epilogue: C/D layout col = lane15 (frag jj), row = quad*4 + r (frag ii)
    float rowb_[8][4];
    if (BIASROW) {
#pragma unroll
        for (int i = 0; i < 8; i++)
#pragma unroll
            for (int r = 0; r < 4; r++)
                rowb_[i][r] = bias0[bm0 + wm * 128 + i * 16 + quad * 4 + r];
    }
#pragma unroll
    for (int jj = 0; jj < 4; jj++) {
        int col = bn0 + wn * 64 + jj * 16 + lane15;
        int seg, cl, cstride;
        if (NSPLIT == 1) { seg = 0; cl = col; cstride = N; }
        else             { seg = col >> 10; cl = col & 1023; cstride = 1024; }
        const float* bp = (seg == 0) ? bias0 : bias1;
        void* cb = (seg == 0) ? C0 : C1;
        u16*   c16 = (u16*)cb   + (long long)b * sCb;
        float* c32 = (float*)cb + (long long)b * sCb;
        float bvc = (!BIASROW && bp) ? bp[cl] : 0.0f;
#pragma unroll
        for (int i = 0; i < 8; i++) {
            int row0 = bm0 + wm * 128 + i * 16 + quad * 4;
#pragma unroll
            for (int r = 0; r < 4; r++) {
                float v = acc[i][jj][r] * scale + (BIASROW ? rowb_[i][r] : bvc);
                if (COUTF32) c32[(long long)(row0 + r) * cstride + cl] = v;
                else         c16[(long long)(row0 + r) * cstride + cl] = f2bf(v);
            }
        }
    }
}

// ---------------------------------------------------------------------------
// Row softmax in-place: 8192 rows of 2048 bf16
// ---------------------------------------------------------------------------
__global__ __launch_bounds__(256) void softmax_k(u16* __restrict__ Sc)
{
    long long row = blockIdx.x;
    u16* s = Sc + row * 2048;
    int t = threadIdx.x;

    uint4 raw = *(const uint4*)(s + t * 8);
    const u16* rp = (const u16*)&raw;
    float v[8];
    float mx = -3.4e38f;
#pragma unroll
    for (int j = 0; j < 8; j++) { v[j] = bf2f(rp[j]); mx = fmaxf(mx, v[j]); }
#pragma unroll
    for (int o = 32; o > 0; o >>= 1) mx = fmaxf(mx, __shfl_xor(mx, o));
    __shared__ float redm[4];
    if ((t & 63) == 0) redm[t >> 6] = mx;
    __syncthreads();
    mx = fmaxf(fmaxf(redm[0], redm[1]), fmaxf(redm[2], redm[3]));

    float sum = 0.0f;
#pragma unroll
    for (int j = 0; j < 8; j++) { v[j] = __expf(v[j] - mx); sum += v[j]; }
#pragma unroll
    for (int o = 32; o > 0; o >>= 1) sum += __shfl_xor(sum, o);
    __shared__ float reds[4];
    if ((t & 63) == 0) reds[t >> 6] = sum;
    __syncthreads();
    sum = reds[0] + reds[1] + reds[2] + reds[3];

    float inv = 1.0f / sum;
    u16 o8[8];
#pragma unroll
    for (int j = 0; j < 8; j++) o8[j] = f2bf(v[j] * inv);
    *(uint4*)(s + t * 8) = *(const uint4*)o8;
}

// ---------------------------------------------------------------------------
// Gate partial: grid (B, 128). Each block: 16 rows of h[b], bf16x8 loads.
// ---------------------------------------------------------------------------
__global__ __launch_bounds__(256) void gate_partial(const u16* __restrict__ h,
                                                    const float* __restrict__ Wg,
                                                    float* __restrict__ part)
{
    int b = blockIdx.x, c = blockIdx.y;
    int t = threadIdx.x;
    int tx = t & 127;
    int ty = t >> 7;
    int d0 = tx * 8;
    const u16* hb = h + (long long)b * 2048 * 1024 + (long long)c * 16 * 1024;

    float wg[8];
#pragma unroll
    for (int j = 0; j < 8; j++) wg[j] = Wg[d0 + j];

    float acc = 0.0f;
    for (int s = ty; s < 16; s += 2) {
        bf16x8 hv = *(const bf16x8*)&hb[(long long)s * 1024 + d0];
        const u16* hp = (const u16*)&hv;
#pragma unroll
        for (int j = 0; j < 8; j++) acc += bf2f(hp[j]) * wg[j];
    }
#pragma unroll
    for (int o = 32; o > 0; o >>= 1) acc += __shfl_xor(acc, o);
    __shared__ float red[4];
    if ((t & 63) == 0) red[t >> 6] = acc;
    __syncthreads();
    if (t == 0) part[b * 128 + c] = red[0] + red[1] + red[2] + red[3];
}

__global__ void gate_final(const float* __restrict__ part,
                           const float* __restrict__ bg, float* __restrict__ outp)
{
    int t = threadIdx.x;
    if (t < 4) {
        float s = 0.0f;
        for (int c = 0; c < 128; c++) s += part[t * 128 + c];
        float v = s * (1.0f / 2048.0f) + bg[0];
        outp[t] = 1.0f / (1.0f + __expf(-v));
    }
}

// ---------------------------------------------------------------------------
// Epilogue: z = relu(mu + eps*exp(0.5*logvar)); out = LN(x+z)*gamma+beta
// ---------------------------------------------------------------------------
__global__ __launch_bounds__(256) void epilogue_k(
    const float* __restrict__ x, const float* __restrict__ ep,
    const float* __restrict__ mu, const float* __restrict__ lv,
    const float* __restrict__ gamma, const float* __restrict__ beta,
    float* __restrict__ out)
{
    long long base = (long long)blockIdx.x * 1024;
    int t = threadIdx.x;
    float y[4];
    float sum = 0.0f, sq = 0.0f;
#pragma unroll
    for (int j = 0; j < 4; j++) {
        int i = j * 256 + t;
        float xv = x[base + i];
        float ev = ep[base + i];
        float m  = mu[base + i];
        float sd = __expf(0.5f * lv[base + i]);
        float z  = fmaxf(m + ev * sd, 0.0f);
        float yy = xv + z;
        y[j] = yy; sum += yy; sq += yy * yy;
    }
#pragma unroll
    for (int o = 32; o > 0; o >>= 1) { sum += __shfl_xor(sum, o); sq += __shfl_xor(sq, o); }
    __shared__ float rs[4], rq[4];
    if ((t & 63) == 0) { rs[t >> 6] = sum; rq[t >> 6] = sq; }
    __syncthreads();
    sum = rs[0] + rs[1] + rs[2] + rs[3];
    sq  = rq[0] + rq[1] + rq[2] + rq[3];
    float mean = sum * (1.0f / 1024.0f);
    float var  = fmaxf(sq * (1.0f / 1024.0f) - mean * mean, 0.0f);
    float rstd = rsqrtf(var + 1e-5f);
#pragma unroll
    for (int j = 0; j < 4; j++) {
        int i = j * 256 + t;
        out[base + i] = (y[j] - mean) * rstd * gamma[i] + beta[i];
    }
}

// ---------------------------------------------------------------------------
extern "C" void kernel_launch(void* const* d_in, const int* in_sizes, int n_in,
                              void* d_out, int out_size, void* d_ws, size_t ws_size,
                              hipStream_t stream)
{
    const float* x     = (const float*)d_in[0];
    const float* ep    = (const float*)d_in[1];
    const float* Wq    = (const float*)d_in[2];
    const float* bq    = (const float*)d_in[3];
    const float* Wk    = (const float*)d_in[4];
    const float* bk    = (const float*)d_in[5];
    const float* Wv    = (const float*)d_in[6];
    const float* bv    = (const float*)d_in[7];
    const float* Wmu   = (const float*)d_in[8];
    const float* bmu   = (const float*)d_in[9];
    const float* Wlv   = (const float*)d_in[10];
    const float* blv   = (const float*)d_in[11];
    const float* Wg    = (const float*)d_in[12];
    const float* bg    = (const float*)d_in[13];
    const float* gamma = (const float*)d_in[14];
    const float* beta  = (const float*)d_in[15];
    float* out = (float*)d_out;

    const int M = 8192;       // B*S
    const int D = 1024;
    const int S = 2048;

    float* mu_out = out + 8388608LL;
    float* lv_out = out + 16777216LL;
    float* pg_out = out + 25165824LL;

    // Scratch overlays (d_out dead regions; ws = h only):
    //  out region: [0-2] xb | Wqb|Wkb (adjacent) | Wvb
    //              [3-5] Sc (33.55MB, overwrites all of the above)
    //              [6-8] part(2KB @+0) + Wmub|Wlvb (adjacent, @+4MB)
    //              [9]   final out f32
    //  mu region: Q | Kb -> then mu_out f32
    //  lv region: VtAll [1024][8192] -> then lv_out f32
    u16* xb   = (u16*)out;
    u16* Wqb  = (u16*)out + 8388608LL;     // [2048][1024]: Wq then Wk
    u16* Wkb  = (u16*)out + 9437184LL;
    u16* Wvb  = (u16*)out + 10485760LL;
    u16* Sc   = (u16*)out;
    u16* Q    = (u16*)mu_out;
    u16* Kb   = (u16*)mu_out + 8388608LL;
    u16* Vt   = (u16*)lv_out;              // VtAll [1024][8192]
    u16* h    = (u16*)d_ws;
    float* part = (float*)out;
    u16* Wmub = (u16*)out + 2097152LL;     // [2048][1024]: Wmu then Wlv
    u16* Wlvb = (u16*)out + 3145728LL;

    dim3 blk(256), blk8(512);

    // 0. Convert x, Wq, Wk, Wv to bf16.
    cvt_bf16_k<<<dim3(2048, 4), blk, 0, stream>>>(
        x,  xb,  2097152LL,
        Wq, Wqb, 262144LL,
        Wk, Wkb, 262144LL,
        Wv, Wvb, 262144LL);

    // 1. Q|K fused: C[8192,2048] = xb @ [Wq;Wk]^T, split cols -> Q, Kb
    gemm256<0, 0, 2><<<dim3(32, 8, 1), blk8, 0, stream>>>(
        xb, Wqb, bq, bk, Q, Kb,
        M, 2048, D, D, 1.0f, 0, 0, 0, 0);

    // 2. VtAll[1024,8192] = Wv @ x^T + bv(row)  (V GEMM + transpose in one)
    gemm256<0, 1, 1><<<dim3(4, 32, 1), blk8, 0, stream>>>(
        Wvb, xb, bv, nullptr, Vt, nullptr,
        D, 8192, D, D, 1.0f, 0, 0, 0, 0);

    // 3. scores = Q @ K^T / 48 per batch -> Sc (xb/W*b now dead)
    gemm256<0, 0, 1><<<dim3(8, 8, 4), blk8, 0, stream>>>(
        Q, Kb, nullptr, nullptr, Sc, nullptr,
        S, S, D, D, 1.0f / 48.0f,
        (long long)S * D, (long long)S * D, (long long)S * S, 0);

    // 4. softmax in place
    softmax_k<<<dim3(8192), blk, 0, stream>>>(Sc);

    // 5. h = P @ V: A=Sc[8192][2048], B=VtAll (ldb=8192, +b*2048 K-offset)
    gemm256<0, 0, 1><<<dim3(32, 4, 1), blk8, 0, stream>>>(
        Sc, Vt, nullptr, nullptr, h, nullptr,
        M, D, S, 8192, 1.0f, 0, 0, 0, 2048);

    // 6. Convert Wmu, Wlv into dead Sc region (adjacent [2048][1024]).
    cvt_bf16_k<<<dim3(512, 2), blk, 0, stream>>>(
        Wmu, Wmub, 262144LL,
        Wlv, Wlvb, 262144LL,
        nullptr, nullptr, 0LL,
        nullptr, nullptr, 0LL);

    // 7. mu|lv fused: C[8192,2048] = h @ [Wmu;Wlv]^T, split -> mu_out, lv_out
    gemm256<1, 0, 2><<<dim3(32, 8, 1), blk8, 0, stream>>>(
        h, Wmub, bmu, blv, (void*)mu_out, (void*)lv_out,
        M, 2048, D, D, 1.0f, 0, 0, 0, 0);

    // 8. gate -> f32 p_gate
    gate_partial<<<dim3(4, 128), blk, 0, stream>>>(h, Wg, part);
    gate_final<<<dim3(1), dim3(64), 0, stream>>>(part, bg, pg_out);

    // 9. out = LN(x + relu(mu + eps*exp(0.5*logvar))) -> f32
    epilogue_k<<<dim3(8192), blk, 0, stream>>>(x, ep, mu_out, lv_out, gamma, beta, out);
}

// Round 7
// 421.211 us; speedup vs baseline: 1.2165x; 1.2165x over previous
//
#include <hip/hip_runtime.h>

typedef unsigned short u16;
typedef __attribute__((ext_vector_type(8))) short bf16x8;
typedef __attribute__((ext_vector_type(4))) float f32x4;

__device__ inline float bf2f(u16 h) {
    union { unsigned u; float f; } v; v.u = ((unsigned)h) << 16; return v.f;
}
__device__ inline u16 f2bf(float f) {
    union { float f; unsigned u; } v; v.f = f;
    unsigned r = v.u + 0x7fffu + ((v.u >> 16) & 1u);
    return (u16)(r >> 16);
}

__device__ inline void gl_lds16(const u16* g, u16* l) {
    __builtin_amdgcn_global_load_lds(
        (const __attribute__((address_space(1))) void*)g,
        (__attribute__((address_space(3))) void*)l, 16, 0, 0);
}

__device__ __forceinline__ void wgbar() {
    asm volatile("" ::: "memory");
    __builtin_amdgcn_s_barrier();
    asm volatile("" ::: "memory");
}
#define VMW(n) asm volatile("s_waitcnt vmcnt(" #n ")" ::: "memory")

// ---------------------------------------------------------------------------
// f32 -> bf16 elementwise convert, up to 4 arrays per launch.
// ---------------------------------------------------------------------------
__global__ __launch_bounds__(256) void cvt_bf16_k(
    const float* __restrict__ s0, u16* __restrict__ d0, long long n0,
    const float* __restrict__ s1, u16* __restrict__ d1, long long n1,
    const float* __restrict__ s2, u16* __restrict__ d2, long long n2,
    const float* __restrict__ s3, u16* __restrict__ d3, long long n3)
{
    int y = blockIdx.y;
    const float* s = (y == 0) ? s0 : (y == 1) ? s1 : (y == 2) ? s2 : s3;
    u16* d         = (y == 0) ? d0 : (y == 1) ? d1 : (y == 2) ? d2 : d3;
    long long n    = (y == 0) ? n0 : (y == 1) ? n1 : (y == 2) ? n2 : n3;
    for (long long i = (long long)blockIdx.x * 256 + threadIdx.x; i < n;
         i += (long long)gridDim.x * 256) {
        float4 v = ((const float4*)s)[i];
        union { u16 h[4]; unsigned long long u; } p;
        p.h[0] = f2bf(v.x); p.h[1] = f2bf(v.y);
        p.h[2] = f2bf(v.z); p.h[3] = f2bf(v.w);
        ((unsigned long long*)d)[i] = p.u;
    }
}

// ---------------------------------------------------------------------------
// 3-deep-ring pipelined GEMM (R4 structure, best measured):
//   C[M,N] = (A[M,K] @ Bt[N,K]^T)*scale + bias
// BM=128, BN=256, BK=64. 512 thr = 8 waves (2M x 4N), wave tile 64x64,
// acc[4][4]. Per K-tile: 2 phases {8 ds_read + 3 stage sites, bar,
// 16 MFMA (setprio), bar}; VMW(6) at phase B confirms t+1 (issued a full
// tile earlier), leaves t+2's 6 loads in flight. Never vmcnt(0) mid-loop.
// LDS ring: 3 slots (A 16KB + B 32KB per slot = 144KB), XOR-swizzled
// (col-group ^= row&7) with inverse-swizzled global source (both-sides rule).
// XCD-aware block swizzle (grid%8==0).
// NSPLIT: output cols in 1024-wide segments -> C0/C1; BIASROW: bias by row.
// bofs_stride: B elem offset += (bm0>>11)*bofs_stride (PV per-batch K-offset).
// ---------------------------------------------------------------------------
#define STA(T, SL2, S)                                                        \
    { const u16* g_ = Ag + (long long)((S) * 64 + w * 8 + srow) * K           \
                      + (long long)(T) * 64 + scol;                           \
      gl_lds16(g_, &As[SL2][(S) * 4096 + w * 512]); }

#define STB(T, SL2, S)                                                        \
    { const u16* g_ = Bg + (long long)(bn0 + (S) * 64 + w * 8 + srow) * ldb   \
                      + (long long)(T) * 64 + scol;                           \
      gl_lds16(g_, &Bs[SL2][(S) * 4096 + w * 512]); }

#define G8_READS(SL, KS)                                                      \
    bf16x8 av[4], bvv[4];                                                     \
    _Pragma("unroll")                                                         \
    for (int ii = 0; ii < 4; ii++)                                            \
        av[ii] = *(const bf16x8*)&As[SL][                                     \
            ((wm * 64 + ii * 16 + lane15) * 64 + (KS) * 32 + quad * 8) ^ xr]; \
    _Pragma("unroll")                                                         \
    for (int jj = 0; jj < 4; jj++)                                            \
        bvv[jj] = *(const bf16x8*)&Bs[SL][                                    \
            ((wn * 64 + jj * 16 + lane15) * 64 + (KS) * 32 + quad * 8) ^ xr];

#define G8_MMA                                                                \
    __builtin_amdgcn_s_setprio(1);                                            \
    _Pragma("unroll")                                                         \
    for (int ii = 0; ii < 4; ii++)                                            \
        _Pragma("unroll")                                                     \
        for (int jj = 0; jj < 4; jj++)                                        \
            acc[ii][jj] = __builtin_amdgcn_mfma_f32_16x16x32_bf16(            \
                av[ii], bvv[jj], acc[ii][jj], 0, 0, 0);                       \
    __builtin_amdgcn_s_setprio(0);

template <int COUTF32, int BIASROW, int NSPLIT>
__global__ __launch_bounds__(512, 2) void gemm8(
    const u16* __restrict__ A, const u16* __restrict__ Bt,
    const float* __restrict__ bias0, const float* __restrict__ bias1,
    void* __restrict__ C0, void* __restrict__ C1,
    int M, int N, int K, int ldb, float scale,
    long long sAb, long long sBb, long long sCb, long long bofs_stride)
{
    __shared__ u16 As[3][8192];    // 3 x 128x64
    __shared__ u16 Bs[3][16384];   // 3 x 256x64

    // XCD-aware bijective block swizzle (requires gx*gy*gz % 8 == 0).
    int gx = gridDim.x, gy = gridDim.y;
    int n = gx * gy * gridDim.z;
    int flat = (blockIdx.z * gy + blockIdx.y) * gx + blockIdx.x;
    int L = (flat & 7) * (n >> 3) + (flat >> 3);
    int bz = L / (gx * gy);
    int rr = L - bz * gx * gy;
    int by = rr / gx, bx = rr - (rr / gx) * gx;

    int bm0 = bx * 128;
    int bn0 = by * 256;
    int b   = bz;
    int tid = threadIdx.x;
    int w = tid >> 6, l = tid & 63;
    int wm = w >> 2;             // M half (64 rows)
    int wn = w & 3;              // N quarter (64 cols)
    int lane15 = l & 15, quad = l >> 4;
    int xr = (l & 7) << 3;       // read-side swizzle (elems); row&7 == l&7

    // staging lane geometry: 8 lanes/row, inverse-swizzled source col-group
    int srow = l >> 3;
    int scol = ((l & 7) ^ srow) * 8;

    const u16* Ag = A  + (long long)b * sAb + (long long)bm0 * K;
    const u16* Bg = Bt + (long long)b * sBb + (long long)(bm0 >> 11) * bofs_stride;

    f32x4 acc[4][4];
#pragma unroll
    for (int i = 0; i < 4; i++)
#pragma unroll
        for (int j = 0; j < 4; j++) acc[i][j] = (f32x4)(0.0f);

    int NT = K >> 6;

    // Prologue: stage tiles 0 and 1 (6 sites each); confirm t0, t1 in flight.
    STA(0, 0, 0); STA(0, 0, 1);
    STB(0, 0, 0); STB(0, 0, 1); STB(0, 0, 2); STB(0, 0, 3);
    STA(1, 1, 0); STA(1, 1, 1);
    STB(1, 1, 0); STB(1, 1, 1); STB(1, 1, 2); STB(1, 1, 3);
    VMW(6);
    wgbar();

    int sl = 0, sl2 = 2;
    for (int t = 0; t < NT; ++t) {
        bool pf = (t + 2 < NT);
        int t2 = t + 2;
        // phase A (ks=0): 8 ds_read + 3 stage sites, bar, 16 MFMA, bar
        {
            G8_READS(sl, 0);
            if (pf) { STA(t2, sl2, 0); STA(t2, sl2, 1); STB(t2, sl2, 0); }
            wgbar();
            G8_MMA;
            wgbar();
        }
        // phase B (ks=1): 8 ds_read + 3 stage sites, VMW(6) confirms t+1
        {
            G8_READS(sl, 1);
            if (pf) {
                STB(t2, sl2, 1); STB(t2, sl2, 2); STB(t2, sl2, 3);
                VMW(6);
            } else {
                VMW(0);
            }
            wgbar();
            G8_MMA;
            wgbar();
        }
        sl  = (sl  == 2) ? 0 : sl + 1;
        sl2 = (sl2 == 2) ? 0 : sl2 + 1;
    }

    // Epilogue: C/D layout col = lane15 (frag jj), row = quad*4 + r (frag ii)
    float rowb_[4][4];
    if (BIASROW) {
#pragma unroll
        for (int i = 0; i < 4; i++)
#pragma unroll
            for (int r = 0; r < 4; r++)
                rowb_[i][r] = bias0[bm0 + wm * 64 + i * 16 + quad * 4 + r];
    }
#pragma unroll
    for (int jj = 0; jj < 4; jj++) {
        int col = bn0 + wn * 64 + jj * 16 + lane15;
        int seg, cl, cstride;
        if (NSPLIT == 1) { seg = 0; cl = col; cstride = N; }
        else             { seg = col >> 10; cl = col & 1023; cstride = 1024; }
        const float* bp = (seg == 0) ? bias0 : bias1;
        void* cb = (seg == 0) ? C0 : C1;
        u16*   c16 = (u16*)cb   + (long long)b * sCb;
        float* c32 = (float*)cb + (long long)b * sCb;
        float bvc = (!BIASROW && bp) ? bp[cl] : 0.0f;
#pragma unroll
        for (int i = 0; i < 4; i++) {
            int row0 = bm0 + wm * 64 + i * 16 + quad * 4;
#pragma unroll
            for (int r = 0; r < 4; r++) {
                float v = acc[i][jj][r] * scale + (BIASROW ? rowb_[i][r] : bvc);
                if (COUTF32) c32[(long long)(row0 + r) * cstride + cl] = v;
                else         c16[(long long)(row0 + r) * cstride + cl] = f2bf(v);
            }
        }
    }
}

// ---------------------------------------------------------------------------
// Row softmax in-place: 8192 rows of 2048 bf16
// ---------------------------------------------------------------------------
__global__ __launch_bounds__(256) void softmax_k(u16* __restrict__ Sc)
{
    long long row = blockIdx.x;
    u16* s = Sc + row * 2048;
    int t = threadIdx.x;

    uint4 raw = *(const uint4*)(s + t * 8);
    const u16* rp = (const u16*)&raw;
    float v[8];
    float mx = -3.4e38f;
#pragma unroll
    for (int j = 0; j < 8; j++) { v[j] = bf2f(rp[j]); mx = fmaxf(mx, v[j]); }
#pragma unroll
    for (int o = 32; o > 0; o >>= 1) mx = fmaxf(mx, __shfl_xor(mx, o));
    __shared__ float redm[4];
    if ((t & 63) == 0) redm[t >> 6] = mx;
    __syncthreads();
    mx = fmaxf(fmaxf(redm[0], redm[1]), fmaxf(redm[2], redm[3]));

    float sum = 0.0f;
#pragma unroll
    for (int j = 0; j < 8; j++) { v[j] = __expf(v[j] - mx); sum += v[j]; }
#pragma unroll
    for (int o = 32; o > 0; o >>= 1) sum += __shfl_xor(sum, o);
    __shared__ float reds[4];
    if ((t & 63) == 0) reds[t >> 6] = sum;
    __syncthreads();
    sum = reds[0] + reds[1] + reds[2] + reds[3];

    float inv = 1.0f / sum;
    u16 o8[8];
#pragma unroll
    for (int j = 0; j < 8; j++) o8[j] = f2bf(v[j] * inv);
    *(uint4*)(s + t * 8) = *(const uint4*)o8;
}

// ---------------------------------------------------------------------------
// Gate partial: grid (B, 128). Each block: 16 rows of h[b], bf16x8 loads.
// ---------------------------------------------------------------------------
__global__ __launch_bounds__(256) void gate_partial(const u16* __restrict__ h,
                                                    const float* __restrict__ Wg,
                                                    float* __restrict__ part)
{
    int b = blockIdx.x, c = blockIdx.y;
    int t = threadIdx.x;
    int tx = t & 127;
    int ty = t >> 7;
    int d0 = tx * 8;
    const u16* hb = h + (long long)b * 2048 * 1024 + (long long)c * 16 * 1024;

    float wg[8];
#pragma unroll
    for (int j = 0; j < 8; j++) wg[j] = Wg[d0 + j];

    float acc = 0.0f;
    for (int s = ty; s < 16; s += 2) {
        bf16x8 hv = *(const bf16x8*)&hb[(long long)s * 1024 + d0];
        const u16* hp = (const u16*)&hv;
#pragma unroll
        for (int j = 0; j < 8; j++) acc += bf2f(hp[j]) * wg[j];
    }
#pragma unroll
    for (int o = 32; o > 0; o >>= 1) acc += __shfl_xor(acc, o);
    __shared__ float red[4];
    if ((t & 63) == 0) red[t >> 6] = acc;
    __syncthreads();
    if (t == 0) part[b * 128 + c] = red[0] + red[1] + red[2] + red[3];
}

__global__ void gate_final(const float* __restrict__ part,
                           const float* __restrict__ bg, float* __restrict__ outp)
{
    int t = threadIdx.x;
    if (t < 4) {
        float s = 0.0f;
        for (int c = 0; c < 128; c++) s += part[t * 128 + c];
        float v = s * (1.0f / 2048.0f) + bg[0];
        outp[t] = 1.0f / (1.0f + __expf(-v));
    }
}

// ---------------------------------------------------------------------------
// Epilogue: z = relu(mu + eps*exp(0.5*logvar)); out = LN(x+z)*gamma+beta
// Vectorized: thread t owns elems [4t, 4t+4) of its 1024-wide row; all
// loads/stores float4 (16B/lane, G13).
// ---------------------------------------------------------------------------
__global__ __launch_bounds__(256) void epilogue_k(
    const float* __restrict__ x, const float* __restrict__ ep,
    const float* __restrict__ mu, const float* __restrict__ lv,
    const float* __restrict__ gamma, const float* __restrict__ beta,
    float* __restrict__ out)
{
    long long base = (long long)blockIdx.x * 1024;
    int t = threadIdx.x;
    int i0 = t * 4;

    float4 xv = *(const float4*)&x[base + i0];
    float4 ev = *(const float4*)&ep[base + i0];
    float4 mv = *(const float4*)&mu[base + i0];
    float4 lw = *(const float4*)&lv[base + i0];

    float y[4];
    y[0] = xv.x + fmaxf(mv.x + ev.x * __expf(0.5f * lw.x), 0.0f);
    y[1] = xv.y + fmaxf(mv.y + ev.y * __expf(0.5f * lw.y), 0.0f);
    y[2] = xv.z + fmaxf(mv.z + ev.z * __expf(0.5f * lw.z), 0.0f);
    y[3] = xv.w + fmaxf(mv.w + ev.w * __expf(0.5f * lw.w), 0.0f);

    float sum = 0.0f, sq = 0.0f;
#pragma unroll
    for (int j = 0; j < 4; j++) { sum += y[j]; sq += y[j] * y[j]; }
#pragma unroll
    for (int o = 32; o > 0; o >>= 1) { sum += __shfl_xor(sum, o); sq += __shfl_xor(sq, o); }
    __shared__ float rs[4], rq[4];
    if ((t & 63) == 0) { rs[t >> 6] = sum; rq[t >> 6] = sq; }
    __syncthreads();
    sum = rs[0] + rs[1] + rs[2] + rs[3];
    sq  = rq[0] + rq[1] + rq[2] + rq[3];
    float mean = sum * (1.0f / 1024.0f);
    float var  = fmaxf(sq * (1.0f / 1024.0f) - mean * mean, 0.0f);
    float rstd = rsqrtf(var + 1e-5f);

    float4 gv = *(const float4*)&gamma[i0];
    float4 bv = *(const float4*)&beta[i0];
    float4 o;
    o.x = (y[0] - mean) * rstd * gv.x + bv.x;
    o.y = (y[1] - mean) * rstd * gv.y + bv.y;
    o.z = (y[2] - mean) * rstd * gv.z + bv.z;
    o.w = (y[3] - mean) * rstd * gv.w + bv.w;
    *(float4*)&out[base + i0] = o;
}

// ---------------------------------------------------------------------------
extern "C" void kernel_launch(void* const* d_in, const int* in_sizes, int n_in,
                              void* d_out, int out_size, void* d_ws, size_t ws_size,
                              hipStream_t stream)
{
    const float* x     = (const float*)d_in[0];
    const float* ep    = (const float*)d_in[1];
    const float* Wq    = (const float*)d_in[2];
    const float* bq    = (const float*)d_in[3];
    const float* Wk    = (const float*)d_in[4];
    const float* bk    = (const float*)d_in[5];
    const float* Wv    = (const float*)d_in[6];
    const float* bv    = (const float*)d_in[7];
    const float* Wmu   = (const float*)d_in[8];
    const float* bmu   = (const float*)d_in[9];
    const float* Wlv   = (const float*)d_in[10];
    const float* blv   = (const float*)d_in[11];
    const float* Wg    = (const float*)d_in[12];
    const float* bg    = (const float*)d_in[13];
    const float* gamma = (const float*)d_in[14];
    const float* beta  = (const float*)d_in[15];
    float* out = (float*)d_out;

    const int M = 8192;       // B*S
    const int D = 1024;
    const int S = 2048;

    float* mu_out = out + 8388608LL;
    float* lv_out = out + 16777216LL;
    float* pg_out = out + 25165824LL;

    // Scratch overlays (d_out dead regions; ws = h only):
    //  out region: [0-2] xb | Wqb|Wkb (adjacent) | Wvb
    //              [3-5] Sc (33.55MB, overwrites all of the above)
    //              [6-8] part(2KB @+0) + Wmub|Wlvb (adjacent, @+4MB)
    //              [9]   final out f32
    //  mu region: Q | Kb -> then mu_out f32
    //  lv region: VtAll [1024][8192] -> then lv_out f32
    u16* xb   = (u16*)out;
    u16* Wqb  = (u16*)out + 8388608LL;     // [2048][1024]: Wq then Wk
    u16* Wkb  = (u16*)out + 9437184LL;
    u16* Wvb  = (u16*)out + 10485760LL;
    u16* Sc   = (u16*)out;
    u16* Q    = (u16*)mu_out;
    u16* Kb   = (u16*)mu_out + 8388608LL;
    u16* Vt   = (u16*)lv_out;              // VtAll [1024][8192]
    u16* h    = (u16*)d_ws;
    float* part = (float*)out;
    u16* Wmub = (u16*)out + 2097152LL;     // [2048][1024]: Wmu then Wlv
    u16* Wlvb = (u16*)out + 3145728LL;

    dim3 blk(256), blk8(512);

    // 0. Convert x, Wq, Wk, Wv to bf16.
    cvt_bf16_k<<<dim3(2048, 4), blk, 0, stream>>>(
        x,  xb,  2097152LL,
        Wq, Wqb, 262144LL,
        Wk, Wkb, 262144LL,
        Wv, Wvb, 262144LL);

    // 1. Q|K fused: C[8192,2048] = xb @ [Wq;Wk]^T, split cols -> Q, Kb
    gemm8<0, 0, 2><<<dim3(64, 8, 1), blk8, 0, stream>>>(
        xb, Wqb, bq, bk, Q, Kb,
        M, 2048, D, D, 1.0f, 0, 0, 0, 0);

    // 2. VtAll[1024,8192] = Wv @ x^T + bv(row)  (V GEMM + transpose in one)
    gemm8<0, 1, 1><<<dim3(8, 32, 1), blk8, 0, stream>>>(
        Wvb, xb, bv, nullptr, Vt, nullptr,
        D, 8192, D, D, 1.0f, 0, 0, 0, 0);

    // 3. scores = Q @ K^T / 48 per batch -> Sc (xb/W*b now dead)
    gemm8<0, 0, 1><<<dim3(16, 8, 4), blk8, 0, stream>>>(
        Q, Kb, nullptr, nullptr, Sc, nullptr,
        S, S, D, D, 1.0f / 48.0f,
        (long long)S * D, (long long)S * D, (long long)S * S, 0);

    // 4. softmax in place
    softmax_k<<<dim3(8192), blk, 0, stream>>>(Sc);

    // 5. h = P @ V: A=Sc[8192][2048], B=VtAll (ldb=8192, +b*2048 K-offset)
    gemm8<0, 0, 1><<<dim3(64, 4, 1), blk8, 0, stream>>>(
        Sc, Vt, nullptr, nullptr, h, nullptr,
        M, D, S, 8192, 1.0f, 0, 0, 0, 2048);

    // 6. Convert Wmu, Wlv into dead Sc region (adjacent [2048][1024]).
    cvt_bf16_k<<<dim3(512, 2), blk, 0, stream>>>(
        Wmu, Wmub, 262144LL,
        Wlv, Wlvb, 262144LL,
        nullptr, nullptr, 0LL,
        nullptr, nullptr, 0LL);

    // 7. mu|lv fused: C[8192,2048] = h @ [Wmu;Wlv]^T, split -> mu_out, lv_out
    gemm8<1, 0, 2><<<dim3(64, 8, 1), blk8, 0, stream>>>(
        h, Wmub, bmu, blv, (void*)mu_out, (void*)lv_out,
        M, 2048, D, D, 1.0f, 0, 0, 0, 0);

    // 8. gate -> f32 p_gate
    gate_partial<<<dim3(4, 128), blk, 0, stream>>>(h, Wg, part);
    gate_final<<<dim3(1), dim3(64), 0, stream>>>(part, bg, pg_out);

    // 9. out = LN(x + relu(mu + eps*exp(0.5*logvar))) -> f32
    epilogue_k<<<dim3(8192), blk, 0, stream>>>(x, ep, mu_out, lv_out, gamma, beta, out);
}

// Round 8
// 420.075 us; speedup vs baseline: 1.2198x; 1.0027x over previous
//
#include <hip/hip_runtime.h>

typedef unsigned short u16;
typedef __attribute__((ext_vector_type(8))) short bf16x8;
typedef __attribute__((ext_vector_type(4))) float f32x4;

__device__ inline float bf2f(u16 h) {
    union { unsigned u; float f; } v; v.u = ((unsigned)h) << 16; return v.f;
}
__device__ inline u16 f2bf(float f) {
    union { float f; unsigned u; } v; v.f = f;
    unsigned r = v.u + 0x7fffu + ((v.u >> 16) & 1u);
    return (u16)(r >> 16);
}

__device__ inline void gl_lds16(const u16* g, u16* l) {
    __builtin_amdgcn_global_load_lds(
        (const __attribute__((address_space(1))) void*)g,
        (__attribute__((address_space(3))) void*)l, 16, 0, 0);
}

__device__ __forceinline__ void wgbar() {
    asm volatile("" ::: "memory");
    __builtin_amdgcn_s_barrier();
    asm volatile("" ::: "memory");
}
#define VMW(n) asm volatile("s_waitcnt vmcnt(" #n ")" ::: "memory")

// ---------------------------------------------------------------------------
// f32 -> bf16 elementwise convert, up to 4 arrays per launch.
// ---------------------------------------------------------------------------
__global__ __launch_bounds__(256) void cvt_bf16_k(
    const float* __restrict__ s0, u16* __restrict__ d0, long long n0,
    const float* __restrict__ s1, u16* __restrict__ d1, long long n1,
    const float* __restrict__ s2, u16* __restrict__ d2, long long n2,
    const float* __restrict__ s3, u16* __restrict__ d3, long long n3)
{
    int y = blockIdx.y;
    const float* s = (y == 0) ? s0 : (y == 1) ? s1 : (y == 2) ? s2 : s3;
    u16* d         = (y == 0) ? d0 : (y == 1) ? d1 : (y == 2) ? d2 : d3;
    long long n    = (y == 0) ? n0 : (y == 1) ? n1 : (y == 2) ? n2 : n3;
    for (long long i = (long long)blockIdx.x * 256 + threadIdx.x; i < n;
         i += (long long)gridDim.x * 256) {
        float4 v = ((const float4*)s)[i];
        union { u16 h[4]; unsigned long long u; } p;
        p.h[0] = f2bf(v.x); p.h[1] = f2bf(v.y);
        p.h[2] = f2bf(v.z); p.h[3] = f2bf(v.w);
        ((unsigned long long*)d)[i] = p.u;
    }
}

// ---------------------------------------------------------------------------
// 3-deep-ring pipelined GEMM (R4 structure, best measured):
//   C[M,N] = (A[M,K] @ Bt[N,K]^T)*scale + bias
// BM=128, BN=256, BK=64. 512 thr = 8 waves (2M x 4N), wave tile 64x64,
// acc[4][4]. Per K-tile: 2 phases {8 ds_read + 3 stage sites, bar,
// 16 MFMA (setprio), bar}; VMW(6) at phase B confirms t+1 (issued a full
// tile earlier), leaves t+2's 6 loads in flight. Never vmcnt(0) mid-loop.
// LDS ring: 3 slots (A 16KB + B 32KB per slot = 144KB), XOR-swizzled
// (col-group ^= row&7) with inverse-swizzled global source (both-sides rule).
// XCD-aware block swizzle (grid%8==0).
// NFAST=1: within each XCD chunk the N-tile index varies fastest, keeping
// each 256KB A-panel L2-hot across its N-tiles (A fetched from HBM once).
// Use for A-heavy GEMMs (A re-read across N was the 3.3x over-fetch).
// NFAST=0: M-tile fastest (keeps B panel hot) - for Vt (big operand is B).
// NSPLIT: output cols in 1024-wide segments -> C0/C1; BIASROW: bias by row.
// bofs_stride: B elem offset += (bm0>>11)*bofs_stride (PV per-batch K-offset).
// ---------------------------------------------------------------------------
#define STA(T, SL2, S)                                                        \
    { const u16* g_ = Ag + (long long)((S) * 64 + w * 8 + srow) * K           \
                      + (long long)(T) * 64 + scol;                           \
      gl_lds16(g_, &As[SL2][(S) * 4096 + w * 512]); }

#define STB(T, SL2, S)                                                        \
    { const u16* g_ = Bg + (long long)(bn0 + (S) * 64 + w * 8 + srow) * ldb   \
                      + (long long)(T) * 64 + scol;                           \
      gl_lds16(g_, &Bs[SL2][(S) * 4096 + w * 512]); }

#define G8_READS(SL, KS)                                                      \
    bf16x8 av[4], bvv[4];                                                     \
    _Pragma("unroll")                                                         \
    for (int ii = 0; ii < 4; ii++)                                            \
        av[ii] = *(const bf16x8*)&As[SL][                                     \
            ((wm * 64 + ii * 16 + lane15) * 64 + (KS) * 32 + quad * 8) ^ xr]; \
    _Pragma("unroll")                                                         \
    for (int jj = 0; jj < 4; jj++)                                            \
        bvv[jj] = *(const bf16x8*)&Bs[SL][                                    \
            ((wn * 64 + jj * 16 + lane15) * 64 + (KS) * 32 + quad * 8) ^ xr];

#define G8_MMA                                                                \
    __builtin_amdgcn_s_setprio(1);                                            \
    _Pragma("unroll")                                                         \
    for (int ii = 0; ii < 4; ii++)                                            \
        _Pragma("unroll")                                                     \
        for (int jj = 0; jj < 4; jj++)                                        \
            acc[ii][jj] = __builtin_amdgcn_mfma_f32_16x16x32_bf16(            \
                av[ii], bvv[jj], acc[ii][jj], 0, 0, 0);                       \
    __builtin_amdgcn_s_setprio(0);

template <int COUTF32, int BIASROW, int NSPLIT, int NFAST>
__global__ __launch_bounds__(512, 2) void gemm8(
    const u16* __restrict__ A, const u16* __restrict__ Bt,
    const float* __restrict__ bias0, const float* __restrict__ bias1,
    void* __restrict__ C0, void* __restrict__ C1,
    int M, int N, int K, int ldb, float scale,
    long long sAb, long long sBb, long long sCb, long long bofs_stride)
{
    __shared__ u16 As[3][8192];    // 3 x 128x64
    __shared__ u16 Bs[3][16384];   // 3 x 256x64

    // XCD-aware bijective block swizzle (requires gx*gy*gz % 8 == 0).
    int gx = gridDim.x, gy = gridDim.y;
    int n = gx * gy * gridDim.z;
    int flat = (blockIdx.z * gy + blockIdx.y) * gx + blockIdx.x;
    int L = (flat & 7) * (n >> 3) + (flat >> 3);
    int bz = L / (gx * gy);
    int rr = L - bz * gx * gy;
    int bx, by;
    if (NFAST) { bx = rr / gy; by = rr - bx * gy; }   // N-tile fastest: A hot
    else       { by = rr / gx; bx = rr - by * gx; }   // M-tile fastest: B hot

    int bm0 = bx * 128;
    int bn0 = by * 256;
    int b   = bz;
    int tid = threadIdx.x;
    int w = tid >> 6, l = tid & 63;
    int wm = w >> 2;             // M half (64 rows)
    int wn = w & 3;              // N quarter (64 cols)
    int lane15 = l & 15, quad = l >> 4;
    int xr = (l & 7) << 3;       // read-side swizzle (elems); row&7 == l&7

    // staging lane geometry: 8 lanes/row, inverse-swizzled source col-group
    int srow = l >> 3;
    int scol = ((l & 7) ^ srow) * 8;

    const u16* Ag = A  + (long long)b * sAb + (long long)bm0 * K;
    const u16* Bg = Bt + (long long)b * sBb + (long long)(bm0 >> 11) * bofs_stride;

    f32x4 acc[4][4];
#pragma unroll
    for (int i = 0; i < 4; i++)
#pragma unroll
        for (int j = 0; j < 4; j++) acc[i][j] = (f32x4)(0.0f);

    int NT = K >> 6;

    // Prologue: stage tiles 0 and 1 (6 sites each); confirm t0, t1 in flight.
    STA(0, 0, 0); STA(0, 0, 1);
    STB(0, 0, 0); STB(0, 0, 1); STB(0, 0, 2); STB(0, 0, 3);
    STA(1, 1, 0); STA(1, 1, 1);
    STB(1, 1, 0); STB(1, 1, 1); STB(1, 1, 2); STB(1, 1, 3);
    VMW(6);
    wgbar();

    int sl = 0, sl2 = 2;
    for (int t = 0; t < NT; ++t) {
        bool pf = (t + 2 < NT);
        int t2 = t + 2;
        // phase A (ks=0): 8 ds_read + 3 stage sites, bar, 16 MFMA, bar
        {
            G8_READS(sl, 0);
            if (pf) { STA(t2, sl2, 0); STA(t2, sl2, 1); STB(t2, sl2, 0); }
            wgbar();
            G8_MMA;
            wgbar();
        }
        // phase B (ks=1): 8 ds_read + 3 stage sites, VMW(6) confirms t+1
        {
            G8_READS(sl, 1);
            if (pf) {
                STB(t2, sl2, 1); STB(t2, sl2, 2); STB(t2, sl2, 3);
                VMW(6);
            } else {
                VMW(0);
            }
            wgbar();
            G8_MMA;
            wgbar();
        }
        sl  = (sl  == 2) ? 0 : sl + 1;
        sl2 = (sl2 == 2) ? 0 : sl2 + 1;
    }

    // Epilogue: C/D layout col = lane15 (frag jj), row = quad*4 + r (frag ii)
    float rowb_[4][4];
    if (BIASROW) {
#pragma unroll
        for (int i = 0; i < 4; i++)
#pragma unroll
            for (int r = 0; r < 4; r++)
                rowb_[i][r] = bias0[bm0 + wm * 64 + i * 16 + quad * 4 + r];
    }
#pragma unroll
    for (int jj = 0; jj < 4; jj++) {
        int col = bn0 + wn * 64 + jj * 16 + lane15;
        int seg, cl, cstride;
        if (NSPLIT == 1) { seg = 0; cl = col; cstride = N; }
        else             { seg = col >> 10; cl = col & 1023; cstride = 1024; }
        const float* bp = (seg == 0) ? bias0 : bias1;
        void* cb = (seg == 0) ? C0 : C1;
        u16*   c16 = (u16*)cb   + (long long)b * sCb;
        float* c32 = (float*)cb + (long long)b * sCb;
        float bvc = (!BIASROW && bp) ? bp[cl] : 0.0f;
#pragma unroll
        for (int i = 0; i < 4; i++) {
            int row0 = bm0 + wm * 64 + i * 16 + quad * 4;
#pragma unroll
            for (int r = 0; r < 4; r++) {
                float v = acc[i][jj][r] * scale + (BIASROW ? rowb_[i][r] : bvc);
                if (COUTF32) c32[(long long)(row0 + r) * cstride + cl] = v;
                else         c16[(long long)(row0 + r) * cstride + cl] = f2bf(v);
            }
        }
    }
}

// ---------------------------------------------------------------------------
// Row softmax in-place: 8192 rows of 2048 bf16
// ---------------------------------------------------------------------------
__global__ __launch_bounds__(256) void softmax_k(u16* __restrict__ Sc)
{
    long long row = blockIdx.x;
    u16* s = Sc + row * 2048;
    int t = threadIdx.x;

    uint4 raw = *(const uint4*)(s + t * 8);
    const u16* rp = (const u16*)&raw;
    float v[8];
    float mx = -3.4e38f;
#pragma unroll
    for (int j = 0; j < 8; j++) { v[j] = bf2f(rp[j]); mx = fmaxf(mx, v[j]); }
#pragma unroll
    for (int o = 32; o > 0; o >>= 1) mx = fmaxf(mx, __shfl_xor(mx, o));
    __shared__ float redm[4];
    if ((t & 63) == 0) redm[t >> 6] = mx;
    __syncthreads();
    mx = fmaxf(fmaxf(redm[0], redm[1]), fmaxf(redm[2], redm[3]));

    float sum = 0.0f;
#pragma unroll
    for (int j = 0; j < 8; j++) { v[j] = __expf(v[j] - mx); sum += v[j]; }
#pragma unroll
    for (int o = 32; o > 0; o >>= 1) sum += __shfl_xor(sum, o);
    __shared__ float reds[4];
    if ((t & 63) == 0) reds[t >> 6] = sum;
    __syncthreads();
    sum = reds[0] + reds[1] + reds[2] + reds[3];

    float inv = 1.0f / sum;
    u16 o8[8];
#pragma unroll
    for (int j = 0; j < 8; j++) o8[j] = f2bf(v[j] * inv);
    *(uint4*)(s + t * 8) = *(const uint4*)o8;
}

// ---------------------------------------------------------------------------
// Gate partial: grid (B, 128). Each block: 16 rows of h[b], bf16x8 loads.
// ---------------------------------------------------------------------------
__global__ __launch_bounds__(256) void gate_partial(const u16* __restrict__ h,
                                                    const float* __restrict__ Wg,
                                                    float* __restrict__ part)
{
    int b = blockIdx.x, c = blockIdx.y;
    int t = threadIdx.x;
    int tx = t & 127;
    int ty = t >> 7;
    int d0 = tx * 8;
    const u16* hb = h + (long long)b * 2048 * 1024 + (long long)c * 16 * 1024;

    float wg[8];
#pragma unroll
    for (int j = 0; j < 8; j++) wg[j] = Wg[d0 + j];

    float acc = 0.0f;
    for (int s = ty; s < 16; s += 2) {
        bf16x8 hv = *(const bf16x8*)&hb[(long long)s * 1024 + d0];
        const u16* hp = (const u16*)&hv;
#pragma unroll
        for (int j = 0; j < 8; j++) acc += bf2f(hp[j]) * wg[j];
    }
#pragma unroll
    for (int o = 32; o > 0; o >>= 1) acc += __shfl_xor(acc, o);
    __shared__ float red[4];
    if ((t & 63) == 0) red[t >> 6] = acc;
    __syncthreads();
    if (t == 0) part[b * 128 + c] = red[0] + red[1] + red[2] + red[3];
}

__global__ void gate_final(const float* __restrict__ part,
                           const float* __restrict__ bg, float* __restrict__ outp)
{
    int t = threadIdx.x;
    if (t < 4) {
        float s = 0.0f;
        for (int c = 0; c < 128; c++) s += part[t * 128 + c];
        float v = s * (1.0f / 2048.0f) + bg[0];
        outp[t] = 1.0f / (1.0f + __expf(-v));
    }
}

// ---------------------------------------------------------------------------
// Epilogue: z = relu(mu + eps*exp(0.5*logvar)); out = LN(x+z)*gamma+beta
// Vectorized: thread t owns elems [4t, 4t+4) of its 1024-wide row; all
// loads/stores float4 (16B/lane, G13).
// ---------------------------------------------------------------------------
__global__ __launch_bounds__(256) void epilogue_k(
    const float* __restrict__ x, const float* __restrict__ ep,
    const float* __restrict__ mu, const float* __restrict__ lv,
    const float* __restrict__ gamma, const float* __restrict__ beta,
    float* __restrict__ out)
{
    long long base = (long long)blockIdx.x * 1024;
    int t = threadIdx.x;
    int i0 = t * 4;

    float4 xv = *(const float4*)&x[base + i0];
    float4 ev = *(const float4*)&ep[base + i0];
    float4 mv = *(const float4*)&mu[base + i0];
    float4 lw = *(const float4*)&lv[base + i0];

    float y[4];
    y[0] = xv.x + fmaxf(mv.x + ev.x * __expf(0.5f * lw.x), 0.0f);
    y[1] = xv.y + fmaxf(mv.y + ev.y * __expf(0.5f * lw.y), 0.0f);
    y[2] = xv.z + fmaxf(mv.z + ev.z * __expf(0.5f * lw.z), 0.0f);
    y[3] = xv.w + fmaxf(mv.w + ev.w * __expf(0.5f * lw.w), 0.0f);

    float sum = 0.0f, sq = 0.0f;
#pragma unroll
    for (int j = 0; j < 4; j++) { sum += y[j]; sq += y[j] * y[j]; }
#pragma unroll
    for (int o = 32; o > 0; o >>= 1) { sum += __shfl_xor(sum, o); sq += __shfl_xor(sq, o); }
    __shared__ float rs[4], rq[4];
    if ((t & 63) == 0) { rs[t >> 6] = sum; rq[t >> 6] = sq; }
    __syncthreads();
    sum = rs[0] + rs[1] + rs[2] + rs[3];
    sq  = rq[0] + rq[1] + rq[2] + rq[3];
    float mean = sum * (1.0f / 1024.0f);
    float var  = fmaxf(sq * (1.0f / 1024.0f) - mean * mean, 0.0f);
    float rstd = rsqrtf(var + 1e-5f);

    float4 gv = *(const float4*)&gamma[i0];
    float4 bv = *(const float4*)&beta[i0];
    float4 o;
    o.x = (y[0] - mean) * rstd * gv.x + bv.x;
    o.y = (y[1] - mean) * rstd * gv.y + bv.y;
    o.z = (y[2] - mean) * rstd * gv.z + bv.z;
    o.w = (y[3] - mean) * rstd * gv.w + bv.w;
    *(float4*)&out[base + i0] = o;
}

// ---------------------------------------------------------------------------
extern "C" void kernel_launch(void* const* d_in, const int* in_sizes, int n_in,
                              void* d_out, int out_size, void* d_ws, size_t ws_size,
                              hipStream_t stream)
{
    const float* x     = (const float*)d_in[0];
    const float* ep    = (const float*)d_in[1];
    const float* Wq    = (const float*)d_in[2];
    const float* bq    = (const float*)d_in[3];
    const float* Wk    = (const float*)d_in[4];
    const float* bk    = (const float*)d_in[5];
    const float* Wv    = (const float*)d_in[6];
    const float* bv    = (const float*)d_in[7];
    const float* Wmu   = (const float*)d_in[8];
    const float* bmu   = (const float*)d_in[9];
    const float* Wlv   = (const float*)d_in[10];
    const float* blv   = (const float*)d_in[11];
    const float* Wg    = (const float*)d_in[12];
    const float* bg    = (const float*)d_in[13];
    const float* gamma = (const float*)d_in[14];
    const float* beta  = (const float*)d_in[15];
    float* out = (float*)d_out;

    const int M = 8192;       // B*S
    const int D = 1024;
    const int S = 2048;

    float* mu_out = out + 8388608LL;
    float* lv_out = out + 16777216LL;
    float* pg_out = out + 25165824LL;

    // Scratch overlays (d_out dead regions; ws = h only):
    //  out region: [0-2] xb | Wqb|Wkb (adjacent) | Wvb
    //              [3-5] Sc (33.55MB, overwrites all of the above)
    //              [6-8] part(2KB @+0) + Wmub|Wlvb (adjacent, @+4MB)
    //              [9]   final out f32
    //  mu region: Q | Kb -> then mu_out f32
    //  lv region: VtAll [1024][8192] -> then lv_out f32
    u16* xb   = (u16*)out;
    u16* Wqb  = (u16*)out + 8388608LL;     // [2048][1024]: Wq then Wk
    u16* Wkb  = (u16*)out + 9437184LL;
    u16* Wvb  = (u16*)out + 10485760LL;
    u16* Sc   = (u16*)out;
    u16* Q    = (u16*)mu_out;
    u16* Kb   = (u16*)mu_out + 8388608LL;
    u16* Vt   = (u16*)lv_out;              // VtAll [1024][8192]
    u16* h    = (u16*)d_ws;
    float* part = (float*)out;
    u16* Wmub = (u16*)out + 2097152LL;     // [2048][1024]: Wmu then Wlv
    u16* Wlvb = (u16*)out + 3145728LL;

    dim3 blk(256), blk8(512);

    // 0. Convert x, Wq, Wk, Wv to bf16.
    cvt_bf16_k<<<dim3(2048, 4), blk, 0, stream>>>(
        x,  xb,  2097152LL,
        Wq, Wqb, 262144LL,
        Wk, Wkb, 262144LL,
        Wv, Wvb, 262144LL);

    // 1. Q|K fused: C[8192,2048] = xb @ [Wq;Wk]^T, split cols -> Q, Kb
    //    NFAST=1: xb panels L2-hot across the 8 N-tiles.
    gemm8<0, 0, 2, 1><<<dim3(64, 8, 1), blk8, 0, stream>>>(
        xb, Wqb, bq, bk, Q, Kb,
        M, 2048, D, D, 1.0f, 0, 0, 0, 0);

    // 2. VtAll[1024,8192] = Wv @ x^T + bv(row)  (V GEMM + transpose in one)
    //    NFAST=0: here B (=xb) is the big operand; keep B panels hot.
    gemm8<0, 1, 1, 0><<<dim3(8, 32, 1), blk8, 0, stream>>>(
        Wvb, xb, bv, nullptr, Vt, nullptr,
        D, 8192, D, D, 1.0f, 0, 0, 0, 0);

    // 3. scores = Q @ K^T / 48 per batch -> Sc (xb/W*b now dead)
    gemm8<0, 0, 1, 1><<<dim3(16, 8, 4), blk8, 0, stream>>>(
        Q, Kb, nullptr, nullptr, Sc, nullptr,
        S, S, D, D, 1.0f / 48.0f,
        (long long)S * D, (long long)S * D, (long long)S * S, 0);

    // 4. softmax in place
    softmax_k<<<dim3(8192), blk, 0, stream>>>(Sc);

    // 5. h = P @ V: A=Sc[8192][2048], B=VtAll (ldb=8192, +b*2048 K-offset)
    gemm8<0, 0, 1, 1><<<dim3(64, 4, 1), blk8, 0, stream>>>(
        Sc, Vt, nullptr, nullptr, h, nullptr,
        M, D, S, 8192, 1.0f, 0, 0, 0, 2048);

    // 6. Convert Wmu, Wlv into dead Sc region (adjacent [2048][1024]).
    cvt_bf16_k<<<dim3(512, 2), blk, 0, stream>>>(
        Wmu, Wmub, 262144LL,
        Wlv, Wlvb, 262144LL,
        nullptr, nullptr, 0LL,
        nullptr, nullptr, 0LL);

    // 7. mu|lv fused: C[8192,2048] = h @ [Wmu;Wlv]^T, split -> mu_out, lv_out
    gemm8<1, 0, 2, 1><<<dim3(64, 8, 1), blk8, 0, stream>>>(
        h, Wmub, bmu, blv, (void*)mu_out, (void*)lv_out,
        M, 2048, D, D, 1.0f, 0, 0, 0, 0);

    // 8. gate -> f32 p_gate
    gate_partial<<<dim3(4, 128), blk, 0, stream>>>(h, Wg, part);
    gate_final<<<dim3(1), dim3(64), 0, stream>>>(part, bg, pg_out);

    // 9. out = LN(x + relu(mu + eps*exp(0.5*logvar))) -> f32
    epilogue_k<<<dim3(8192), blk, 0, stream>>>(x, ep, mu_out, lv_out, gamma, beta, out);
}

// Round 9
// 416.966 us; speedup vs baseline: 1.2289x; 1.0075x over previous
//
#include <hip/hip_runtime.h>

typedef unsigned short u16;
typedef __attribute__((ext_vector_type(8))) short bf16x8;
typedef __attribute__((ext_vector_type(4))) float f32x4;

__device__ inline float bf2f(u16 h) {
    union { unsigned u; float f; } v; v.u = ((unsigned)h) << 16; return v.f;
}
__device__ inline u16 f2bf(float f) {
    union { float f; unsigned u; } v; v.f = f;
    unsigned r = v.u + 0x7fffu + ((v.u >> 16) & 1u);
    return (u16)(r >> 16);
}

__device__ inline void gl_lds16(const u16* g, u16* l) {
    __builtin_amdgcn_global_load_lds(
        (const __attribute__((address_space(1))) void*)g,
        (__attribute__((address_space(3))) void*)l, 16, 0, 0);
}

__device__ __forceinline__ void wgbar() {
    asm volatile("" ::: "memory");
    __builtin_amdgcn_s_barrier();
    asm volatile("" ::: "memory");
}
#define VMW(n) asm volatile("s_waitcnt vmcnt(" #n ")" ::: "memory")

// ---------------------------------------------------------------------------
// f32 -> bf16 elementwise convert, up to 4 arrays per launch.
// ---------------------------------------------------------------------------
__global__ __launch_bounds__(256) void cvt_bf16_k(
    const float* __restrict__ s0, u16* __restrict__ d0, long long n0,
    const float* __restrict__ s1, u16* __restrict__ d1, long long n1,
    const float* __restrict__ s2, u16* __restrict__ d2, long long n2,
    const float* __restrict__ s3, u16* __restrict__ d3, long long n3)
{
    int y = blockIdx.y;
    const float* s = (y == 0) ? s0 : (y == 1) ? s1 : (y == 2) ? s2 : s3;
    u16* d         = (y == 0) ? d0 : (y == 1) ? d1 : (y == 2) ? d2 : d3;
    long long n    = (y == 0) ? n0 : (y == 1) ? n1 : (y == 2) ? n2 : n3;
    for (long long i = (long long)blockIdx.x * 256 + threadIdx.x; i < n;
         i += (long long)gridDim.x * 256) {
        float4 v = ((const float4*)s)[i];
        union { u16 h[4]; unsigned long long u; } p;
        p.h[0] = f2bf(v.x); p.h[1] = f2bf(v.y);
        p.h[2] = f2bf(v.z); p.h[3] = f2bf(v.w);
        ((unsigned long long*)d)[i] = p.u;
    }
}

// ---------------------------------------------------------------------------
// Occupancy-3 ring GEMM: C[M,N] = (A[M,K] @ Bt[N,K]^T)*scale + bias
// BM=128, BN=128, BK=32. 256 thr = 4 waves (2M x 2N), wave tile 64x64,
// acc[4][4]. LDS ring: 3 slots x (A 8KB + B 8KB) = 48KB -> 3 blocks/CU
// (12 waves/CU): co-resident blocks hide each other's barrier stalls
// (m97 mechanism), on top of the R4 counted-vmcnt ring.
// Per K-tile, ONE phase: {8 ds_read ; stage t+2 (4 sites) ; VMW(4) ; bar ;
// 16 MFMA (setprio) ; bar}. Ledger: in-flight after staging = t+1(4)+t+2(4);
// VMW(4) confirms t+1. Drain VMW(0) only at t=NT-2; nothing at t=NT-1.
// Swizzle (both-sides): 32-elem rows, col-group ^= row&3; staged via
// inverse-swizzled global source col; read applies same XOR.
// XCD-aware block swizzle (grid%8==0); NFAST as in R8.
// NSPLIT: output cols in 1024-wide segments -> C0/C1; BIASROW: bias by row.
// bofs_stride: B elem offset += (bm0>>11)*bofs_stride (PV per-batch K-offset).
// ---------------------------------------------------------------------------
#define OSTA(T, SL2, S)                                                       \
    { const u16* g_ = Ag + (long long)((S) * 64 + w * 16 + orow) * K          \
                      + (long long)(T) * 32 + oscol;                          \
      gl_lds16(g_, &As[SL2][(S) * 2048 + w * 512]); }

#define OSTB(T, SL2, S)                                                       \
    { const u16* g_ = Bg + (long long)(bn0 + (S) * 64 + w * 16 + orow) * ldb  \
                      + (long long)(T) * 32 + oscol;                          \
      gl_lds16(g_, &Bs[SL2][(S) * 2048 + w * 512]); }

template <int COUTF32, int BIASROW, int NSPLIT, int NFAST>
__global__ __launch_bounds__(256, 3) void gemm_o(
    const u16* __restrict__ A, const u16* __restrict__ Bt,
    const float* __restrict__ bias0, const float* __restrict__ bias1,
    void* __restrict__ C0, void* __restrict__ C1,
    int M, int N, int K, int ldb, float scale,
    long long sAb, long long sBb, long long sCb, long long bofs_stride)
{
    __shared__ u16 As[3][4096];    // 3 x 128x32
    __shared__ u16 Bs[3][4096];    // 3 x 128x32

    // XCD-aware bijective block swizzle (requires gx*gy*gz % 8 == 0).
    int gx = gridDim.x, gy = gridDim.y;
    int n = gx * gy * gridDim.z;
    int flat = (blockIdx.z * gy + blockIdx.y) * gx + blockIdx.x;
    int L = (flat & 7) * (n >> 3) + (flat >> 3);
    int bz = L / (gx * gy);
    int rr = L - bz * gx * gy;
    int bx, by;
    if (NFAST) { bx = rr / gy; by = rr - bx * gy; }   // N-tile fastest: A hot
    else       { by = rr / gx; bx = rr - by * gx; }   // M-tile fastest: B hot

    int bm0 = bx * 128;
    int bn0 = by * 128;
    int b   = bz;
    int tid = threadIdx.x;
    int w = tid >> 6, l = tid & 63;
    int wm = w >> 1;             // M half (64 rows)
    int wn = w & 1;              // N half (64 cols)
    int lane15 = l & 15, quad = l >> 4;
    int xr = (l & 3) << 3;       // read swizzle (elems); read row&3 == l&3

    // staging lane geometry: 4 lanes/row (16 rows/wave), inverse-swizzled col
    int orow  = l >> 2;
    int oscol = ((l & 3) ^ (orow & 3)) * 8;

    const u16* Ag = A  + (long long)b * sAb + (long long)bm0 * K;
    const u16* Bg = Bt + (long long)b * sBb + (long long)(bm0 >> 11) * bofs_stride;

    f32x4 acc[4][4];
#pragma unroll
    for (int i = 0; i < 4; i++)
#pragma unroll
        for (int j = 0; j < 4; j++) acc[i][j] = (f32x4)(0.0f);

    int NT = K >> 5;

    // Prologue: stage tiles 0 and 1 (4 sites each); confirm t0, t1 in flight.
    OSTA(0, 0, 0); OSTA(0, 0, 1); OSTB(0, 0, 0); OSTB(0, 0, 1);
    OSTA(1, 1, 0); OSTA(1, 1, 1); OSTB(1, 1, 0); OSTB(1, 1, 1);
    VMW(4);
    wgbar();

    int sl = 0, sl2 = 2;
    for (int t = 0; t < NT; ++t) {
        // 8 ds_read_b128 for tile t (confirmed by previous tile's VMW)
        bf16x8 av[4], bvv[4];
#pragma unroll
        for (int ii = 0; ii < 4; ii++)
            av[ii] = *(const bf16x8*)&As[sl][
                (wm * 64 + ii * 16 + lane15) * 32 + ((quad * 8) ^ xr)];
#pragma unroll
        for (int jj = 0; jj < 4; jj++)
            bvv[jj] = *(const bf16x8*)&Bs[sl][
                (wn * 64 + jj * 16 + lane15) * 32 + ((quad * 8) ^ xr)];

        if (t + 2 < NT) {
            int t2 = t + 2;
            OSTA(t2, sl2, 0); OSTA(t2, sl2, 1);
            OSTB(t2, sl2, 0); OSTB(t2, sl2, 1);
            VMW(4);              // confirm t+1; t+2's 4 stay in flight
        } else if (t + 1 < NT) {
            VMW(0);              // tail drain (once, at t = NT-2)
        }
        wgbar();

        __builtin_amdgcn_s_setprio(1);
#pragma unroll
        for (int ii = 0; ii < 4; ii++)
#pragma unroll
            for (int jj = 0; jj < 4; jj++)
                acc[ii][jj] = __builtin_amdgcn_mfma_f32_16x16x32_bf16(
                    av[ii], bvv[jj], acc[ii][jj], 0, 0, 0);
        __builtin_amdgcn_s_setprio(0);
        wgbar();

        sl  = (sl  == 2) ? 0 : sl + 1;
        sl2 = (sl2 == 2) ? 0 : sl2 + 1;
    }

    // Epilogue: C/D layout col = lane15 (frag jj), row = quad*4 + r (frag ii)
    float rowb_[4][4];
    if (BIASROW) {
#pragma unroll
        for (int i = 0; i < 4; i++)
#pragma unroll
            for (int r = 0; r < 4; r++)
                rowb_[i][r] = bias0[bm0 + wm * 64 + i * 16 + quad * 4 + r];
    }
#pragma unroll
    for (int jj = 0; jj < 4; jj++) {
        int col = bn0 + wn * 64 + jj * 16 + lane15;
        int seg, cl, cstride;
        if (NSPLIT == 1) { seg = 0; cl = col; cstride = N; }
        else             { seg = col >> 10; cl = col & 1023; cstride = 1024; }
        const float* bp = (seg == 0) ? bias0 : bias1;
        void* cb = (seg == 0) ? C0 : C1;
        u16*   c16 = (u16*)cb   + (long long)b * sCb;
        float* c32 = (float*)cb + (long long)b * sCb;
        float bvc = (!BIASROW && bp) ? bp[cl] : 0.0f;
#pragma unroll
        for (int i = 0; i < 4; i++) {
            int row0 = bm0 + wm * 64 + i * 16 + quad * 4;
#pragma unroll
            for (int r = 0; r < 4; r++) {
                float v = acc[i][jj][r] * scale + (BIASROW ? rowb_[i][r] : bvc);
                if (COUTF32) c32[(long long)(row0 + r) * cstride + cl] = v;
                else         c16[(long long)(row0 + r) * cstride + cl] = f2bf(v);
            }
        }
    }
}

// ---------------------------------------------------------------------------
// Row softmax in-place: 8192 rows of 2048 bf16
// ---------------------------------------------------------------------------
__global__ __launch_bounds__(256) void softmax_k(u16* __restrict__ Sc)
{
    long long row = blockIdx.x;
    u16* s = Sc + row * 2048;
    int t = threadIdx.x;

    uint4 raw = *(const uint4*)(s + t * 8);
    const u16* rp = (const u16*)&raw;
    float v[8];
    float mx = -3.4e38f;
#pragma unroll
    for (int j = 0; j < 8; j++) { v[j] = bf2f(rp[j]); mx = fmaxf(mx, v[j]); }
#pragma unroll
    for (int o = 32; o > 0; o >>= 1) mx = fmaxf(mx, __shfl_xor(mx, o));
    __shared__ float redm[4];
    if ((t & 63) == 0) redm[t >> 6] = mx;
    __syncthreads();
    mx = fmaxf(fmaxf(redm[0], redm[1]), fmaxf(redm[2], redm[3]));

    float sum = 0.0f;
#pragma unroll
    for (int j = 0; j < 8; j++) { v[j] = __expf(v[j] - mx); sum += v[j]; }
#pragma unroll
    for (int o = 32; o > 0; o >>= 1) sum += __shfl_xor(sum, o);
    __shared__ float reds[4];
    if ((t & 63) == 0) reds[t >> 6] = sum;
    __syncthreads();
    sum = reds[0] + reds[1] + reds[2] + reds[3];

    float inv = 1.0f / sum;
    u16 o8[8];
#pragma unroll
    for (int j = 0; j < 8; j++) o8[j] = f2bf(v[j] * inv);
    *(uint4*)(s + t * 8) = *(const uint4*)o8;
}

// ---------------------------------------------------------------------------
// Gate partial: grid (B, 128). Each block: 16 rows of h[b], bf16x8 loads.
// ---------------------------------------------------------------------------
__global__ __launch_bounds__(256) void gate_partial(const u16* __restrict__ h,
                                                    const float* __restrict__ Wg,
                                                    float* __restrict__ part)
{
    int b = blockIdx.x, c = blockIdx.y;
    int t = threadIdx.x;
    int tx = t & 127;
    int ty = t >> 7;
    int d0 = tx * 8;
    const u16* hb = h + (long long)b * 2048 * 1024 + (long long)c * 16 * 1024;

    float wg[8];
#pragma unroll
    for (int j = 0; j < 8; j++) wg[j] = Wg[d0 + j];

    float acc = 0.0f;
    for (int s = ty; s < 16; s += 2) {
        bf16x8 hv = *(const bf16x8*)&hb[(long long)s * 1024 + d0];
        const u16* hp = (const u16*)&hv;
#pragma unroll
        for (int j = 0; j < 8; j++) acc += bf2f(hp[j]) * wg[j];
    }
#pragma unroll
    for (int o = 32; o > 0; o >>= 1) acc += __shfl_xor(acc, o);
    __shared__ float red[4];
    if ((t & 63) == 0) red[t >> 6] = acc;
    __syncthreads();
    if (t == 0) part[b * 128 + c] = red[0] + red[1] + red[2] + red[3];
}

__global__ void gate_final(const float* __restrict__ part,
                           const float* __restrict__ bg, float* __restrict__ outp)
{
    int t = threadIdx.x;
    if (t < 4) {
        float s = 0.0f;
        for (int c = 0; c < 128; c++) s += part[t * 128 + c];
        float v = s * (1.0f / 2048.0f) + bg[0];
        outp[t] = 1.0f / (1.0f + __expf(-v));
    }
}

// ---------------------------------------------------------------------------
// Epilogue: z = relu(mu + eps*exp(0.5*logvar)); out = LN(x+z)*gamma+beta
// Vectorized: thread t owns elems [4t, 4t+4); all loads/stores float4.
// ---------------------------------------------------------------------------
__global__ __launch_bounds__(256) void epilogue_k(
    const float* __restrict__ x, const float* __restrict__ ep,
    const float* __restrict__ mu, const float* __restrict__ lv,
    const float* __restrict__ gamma, const float* __restrict__ beta,
    float* __restrict__ out)
{
    long long base = (long long)blockIdx.x * 1024;
    int t = threadIdx.x;
    int i0 = t * 4;

    float4 xv = *(const float4*)&x[base + i0];
    float4 ev = *(const float4*)&ep[base + i0];
    float4 mv = *(const float4*)&mu[base + i0];
    float4 lw = *(const float4*)&lv[base + i0];

    float y[4];
    y[0] = xv.x + fmaxf(mv.x + ev.x * __expf(0.5f * lw.x), 0.0f);
    y[1] = xv.y + fmaxf(mv.y + ev.y * __expf(0.5f * lw.y), 0.0f);
    y[2] = xv.z + fmaxf(mv.z + ev.z * __expf(0.5f * lw.z), 0.0f);
    y[3] = xv.w + fmaxf(mv.w + ev.w * __expf(0.5f * lw.w), 0.0f);

    float sum = 0.0f, sq = 0.0f;
#pragma unroll
    for (int j = 0; j < 4; j++) { sum += y[j]; sq += y[j] * y[j]; }
#pragma unroll
    for (int o = 32; o > 0; o >>= 1) { sum += __shfl_xor(sum, o); sq += __shfl_xor(sq, o); }
    __shared__ float rs[4], rq[4];
    if ((t & 63) == 0) { rs[t >> 6] = sum; rq[t >> 6] = sq; }
    __syncthreads();
    sum = rs[0] + rs[1] + rs[2] + rs[3];
    sq  = rq[0] + rq[1] + rq[2] + rq[3];
    float mean = sum * (1.0f / 1024.0f);
    float var  = fmaxf(sq * (1.0f / 1024.0f) - mean * mean, 0.0f);
    float rstd = rsqrtf(var + 1e-5f);

    float4 gv = *(const float4*)&gamma[i0];
    float4 bv = *(const float4*)&beta[i0];
    float4 o;
    o.x = (y[0] - mean) * rstd * gv.x + bv.x;
    o.y = (y[1] - mean) * rstd * gv.y + bv.y;
    o.z = (y[2] - mean) * rstd * gv.z + bv.z;
    o.w = (y[3] - mean) * rstd * gv.w + bv.w;
    *(float4*)&out[base + i0] = o;
}

// ---------------------------------------------------------------------------
extern "C" void kernel_launch(void* const* d_in, const int* in_sizes, int n_in,
                              void* d_out, int out_size, void* d_ws, size_t ws_size,
                              hipStream_t stream)
{
    const float* x     = (const float*)d_in[0];
    const float* ep    = (const float*)d_in[1];
    const float* Wq    = (const float*)d_in[2];
    const float* bq    = (const float*)d_in[3];
    const float* Wk    = (const float*)d_in[4];
    const float* bk    = (const float*)d_in[5];
    const float* Wv    = (const float*)d_in[6];
    const float* bv    = (const float*)d_in[7];
    const float* Wmu   = (const float*)d_in[8];
    const float* bmu   = (const float*)d_in[9];
    const float* Wlv   = (const float*)d_in[10];
    const float* blv   = (const float*)d_in[11];
    const float* Wg    = (const float*)d_in[12];
    const float* bg    = (const float*)d_in[13];
    const float* gamma = (const float*)d_in[14];
    const float* beta  = (const float*)d_in[15];
    float* out = (float*)d_out;

    const int M = 8192;       // B*S
    const int D = 1024;
    const int S = 2048;

    float* mu_out = out + 8388608LL;
    float* lv_out = out + 16777216LL;
    float* pg_out = out + 25165824LL;

    // Scratch overlays (d_out dead regions; ws = h only):
    //  out region: [0-2] xb | Wqb|Wkb (adjacent) | Wvb
    //              [3-5] Sc (33.55MB, overwrites all of the above)
    //              [6-8] part(2KB @+0) + Wmub|Wlvb (adjacent, @+4MB)
    //              [9]   final out f32
    //  mu region: Q | Kb -> then mu_out f32
    //  lv region: VtAll [1024][8192] -> then lv_out f32
    u16* xb   = (u16*)out;
    u16* Wqb  = (u16*)out + 8388608LL;     // [2048][1024]: Wq then Wk
    u16* Wkb  = (u16*)out + 9437184LL;
    u16* Wvb  = (u16*)out + 10485760LL;
    u16* Sc   = (u16*)out;
    u16* Q    = (u16*)mu_out;
    u16* Kb   = (u16*)mu_out + 8388608LL;
    u16* Vt   = (u16*)lv_out;              // VtAll [1024][8192]
    u16* h    = (u16*)d_ws;
    float* part = (float*)out;
    u16* Wmub = (u16*)out + 2097152LL;     // [2048][1024]: Wmu then Wlv
    u16* Wlvb = (u16*)out + 3145728LL;

    dim3 blk(256);

    // 0. Convert x, Wq, Wk, Wv to bf16.
    cvt_bf16_k<<<dim3(2048, 4), blk, 0, stream>>>(
        x,  xb,  2097152LL,
        Wq, Wqb, 262144LL,
        Wk, Wkb, 262144LL,
        Wv, Wvb, 262144LL);

    // 1. Q|K fused: C[8192,2048] = xb @ [Wq;Wk]^T, split cols -> Q, Kb
    gemm_o<0, 0, 2, 1><<<dim3(64, 16, 1), blk, 0, stream>>>(
        xb, Wqb, bq, bk, Q, Kb,
        M, 2048, D, D, 1.0f, 0, 0, 0, 0);

    // 2. VtAll[1024,8192] = Wv @ x^T + bv(row)  (V GEMM + transpose in one)
    gemm_o<0, 1, 1, 0><<<dim3(8, 64, 1), blk, 0, stream>>>(
        Wvb, xb, bv, nullptr, Vt, nullptr,
        D, 8192, D, D, 1.0f, 0, 0, 0, 0);

    // 3. scores = Q @ K^T / 48 per batch -> Sc (xb/W*b now dead)
    gemm_o<0, 0, 1, 1><<<dim3(16, 16, 4), blk, 0, stream>>>(
        Q, Kb, nullptr, nullptr, Sc, nullptr,
        S, S, D, D, 1.0f / 48.0f,
        (long long)S * D, (long long)S * D, (long long)S * S, 0);

    // 4. softmax in place
    softmax_k<<<dim3(8192), blk, 0, stream>>>(Sc);

    // 5. h = P @ V: A=Sc[8192][2048], B=VtAll (ldb=8192, +b*2048 K-offset)
    gemm_o<0, 0, 1, 1><<<dim3(64, 8, 1), blk, 0, stream>>>(
        Sc, Vt, nullptr, nullptr, h, nullptr,
        M, D, S, 8192, 1.0f, 0, 0, 0, 2048);

    // 6. Convert Wmu, Wlv into dead Sc region (adjacent [2048][1024]).
    cvt_bf16_k<<<dim3(512, 2), blk, 0, stream>>>(
        Wmu, Wmub, 262144LL,
        Wlv, Wlvb, 262144LL,
        nullptr, nullptr, 0LL,
        nullptr, nullptr, 0LL);

    // 7. mu|lv fused: C[8192,2048] = h @ [Wmu;Wlv]^T, split -> mu_out, lv_out
    gemm_o<1, 0, 2, 1><<<dim3(64, 16, 1), blk, 0, stream>>>(
        h, Wmub, bmu, blv, (void*)mu_out, (void*)lv_out,
        M, 2048, D, D, 1.0f, 0, 0, 0, 0);

    // 8. gate -> f32 p_gate
    gate_partial<<<dim3(4, 128), blk, 0, stream>>>(h, Wg, part);
    gate_final<<<dim3(1), dim3(64), 0, stream>>>(part, bg, pg_out);

    // 9. out = LN(x + relu(mu + eps*exp(0.5*logvar))) -> f32
    epilogue_k<<<dim3(8192), blk, 0, stream>>>(x, ep, mu_out, lv_out, gamma, beta, out);
}

// Round 10
// 407.412 us; speedup vs baseline: 1.2577x; 1.0234x over previous
//
#include <hip/hip_runtime.h>

typedef unsigned short u16;
typedef __attribute__((ext_vector_type(8))) short bf16x8;
typedef __attribute__((ext_vector_type(4))) float f32x4;

__device__ inline float bf2f(u16 h) {
    union { unsigned u; float f; } v; v.u = ((unsigned)h) << 16; return v.f;
}
__device__ inline u16 f2bf(float f) {
    union { float f; unsigned u; } v; v.f = f;
    unsigned r = v.u + 0x7fffu + ((v.u >> 16) & 1u);
    return (u16)(r >> 16);
}

__device__ inline void gl_lds16(const u16* g, u16* l) {
    __builtin_amdgcn_global_load_lds(
        (const __attribute__((address_space(1))) void*)g,
        (__attribute__((address_space(3))) void*)l, 16, 0, 0);
}

__device__ __forceinline__ void wgbar() {
    asm volatile("" ::: "memory");
    __builtin_amdgcn_s_barrier();
    asm volatile("" ::: "memory");
}
#define VMW(n) asm volatile("s_waitcnt vmcnt(" #n ")" ::: "memory")

// ---------------------------------------------------------------------------
// f32 -> bf16 elementwise convert, up to 4 arrays per launch.
// ---------------------------------------------------------------------------
__global__ __launch_bounds__(256) void cvt_bf16_k(
    const float* __restrict__ s0, u16* __restrict__ d0, long long n0,
    const float* __restrict__ s1, u16* __restrict__ d1, long long n1,
    const float* __restrict__ s2, u16* __restrict__ d2, long long n2,
    const float* __restrict__ s3, u16* __restrict__ d3, long long n3)
{
    int y = blockIdx.y;
    const float* s = (y == 0) ? s0 : (y == 1) ? s1 : (y == 2) ? s2 : s3;
    u16* d         = (y == 0) ? d0 : (y == 1) ? d1 : (y == 2) ? d2 : d3;
    long long n    = (y == 0) ? n0 : (y == 1) ? n1 : (y == 2) ? n2 : n3;
    for (long long i = (long long)blockIdx.x * 256 + threadIdx.x; i < n;
         i += (long long)gridDim.x * 256) {
        float4 v = ((const float4*)s)[i];
        union { u16 h[4]; unsigned long long u; } p;
        p.h[0] = f2bf(v.x); p.h[1] = f2bf(v.y);
        p.h[2] = f2bf(v.z); p.h[3] = f2bf(v.w);
        ((unsigned long long*)d)[i] = p.u;
    }
}

// ---------------------------------------------------------------------------
// Occupancy-3 ring GEMM body (R9 structure, byte-identical schedule):
//   C[M,N] = (A[M,K] @ Bt[N,K]^T)*scale + bias
// BM=128, BN=128, BK=32. 256 thr = 4 waves (2M x 2N), wave tile 64x64,
// acc[4][4]. LDS ring: 3 slots x (A 8KB + B 8KB) = 48KB (kernel-owned,
// passed in so multiple instantiations in one kernel share one allocation)
// -> 3 blocks/CU. Per K-tile: {8 ds_read ; stage t+2 (4 sites) ; VMW(4) ;
// bar ; 16 MFMA (setprio) ; bar}. VMW(0) only at t=NT-2.
// Swizzle (both-sides): col-group ^= row&3, inverse-swizzled global source.
// GATE: epilogue also accumulates sum(v*Wg[col]) for this tile and does one
// atomicAdd into gatebuf[bm0>>11] (PV: batch = global row >> 11).
// ---------------------------------------------------------------------------
#define OSTA(T, SL2, S)                                                       \
    { const u16* g_ = Ag + (long long)((S) * 64 + w * 16 + orow) * K          \
                      + (long long)(T) * 32 + oscol;                          \
      gl_lds16(g_, &As[(SL2) * 4096 + (S) * 2048 + w * 512]); }

#define OSTB(T, SL2, S)                                                       \
    { const u16* g_ = Bg + (long long)(bn0 + (S) * 64 + w * 16 + orow) * ldb  \
                      + (long long)(T) * 32 + oscol;                          \
      gl_lds16(g_, &Bs[(SL2) * 4096 + (S) * 2048 + w * 512]); }

template <int COUTF32, int BIASROW, int NSPLIT, int GATE>
__device__ __forceinline__ void gemm_body(
    const u16* __restrict__ A, const u16* __restrict__ Bt,
    const float* __restrict__ bias0, const float* __restrict__ bias1,
    void* __restrict__ C0, void* __restrict__ C1,
    int M, int N, int K, int ldb, float scale,
    long long sAb, long long sBb, long long sCb, long long bofs_stride,
    int bx, int by, int bz, int tid,
    const float* __restrict__ Wg, float* __restrict__ gatebuf,
    u16* lds)
{
    u16* As = lds;              // 3 x 4096
    u16* Bs = lds + 12288;      // 3 x 4096

    int bm0 = bx * 128;
    int bn0 = by * 128;
    int b   = bz;
    int w = tid >> 6, l = tid & 63;
    int wm = w >> 1;             // M half (64 rows)
    int wn = w & 1;              // N half (64 cols)
    int lane15 = l & 15, quad = l >> 4;
    int xr = (l & 3) << 3;       // read swizzle (elems); read row&3 == l&3

    // staging lane geometry: 4 lanes/row (16 rows/wave), inverse-swizzled col
    int orow  = l >> 2;
    int oscol = ((l & 3) ^ (orow & 3)) * 8;

    const u16* Ag = A  + (long long)b * sAb + (long long)bm0 * K;
    const u16* Bg = Bt + (long long)b * sBb + (long long)(bm0 >> 11) * bofs_stride;

    f32x4 acc[4][4];
#pragma unroll
    for (int i = 0; i < 4; i++)
#pragma unroll
        for (int j = 0; j < 4; j++) acc[i][j] = (f32x4)(0.0f);

    int NT = K >> 5;

    // Prologue: stage tiles 0 and 1 (4 sites each); confirm t0, t1 in flight.
    OSTA(0, 0, 0); OSTA(0, 0, 1); OSTB(0, 0, 0); OSTB(0, 0, 1);
    OSTA(1, 1, 0); OSTA(1, 1, 1); OSTB(1, 1, 0); OSTB(1, 1, 1);
    VMW(4);
    wgbar();

    int sl = 0, sl2 = 2;
    for (int t = 0; t < NT; ++t) {
        bf16x8 av[4], bvv[4];
#pragma unroll
        for (int ii = 0; ii < 4; ii++)
            av[ii] = *(const bf16x8*)&As[sl * 4096 +
                (wm * 64 + ii * 16 + lane15) * 32 + ((quad * 8) ^ xr)];
#pragma unroll
        for (int jj = 0; jj < 4; jj++)
            bvv[jj] = *(const bf16x8*)&Bs[sl * 4096 +
                (wn * 64 + jj * 16 + lane15) * 32 + ((quad * 8) ^ xr)];

        if (t + 2 < NT) {
            int t2 = t + 2;
            OSTA(t2, sl2, 0); OSTA(t2, sl2, 1);
            OSTB(t2, sl2, 0); OSTB(t2, sl2, 1);
            VMW(4);              // confirm t+1; t+2's 4 stay in flight
        } else if (t + 1 < NT) {
            VMW(0);              // tail drain (once, at t = NT-2)
        }
        wgbar();

        __builtin_amdgcn_s_setprio(1);
#pragma unroll
        for (int ii = 0; ii < 4; ii++)
#pragma unroll
            for (int jj = 0; jj < 4; jj++)
                acc[ii][jj] = __builtin_amdgcn_mfma_f32_16x16x32_bf16(
                    av[ii], bvv[jj], acc[ii][jj], 0, 0, 0);
        __builtin_amdgcn_s_setprio(0);
        wgbar();

        sl  = (sl  == 2) ? 0 : sl + 1;
        sl2 = (sl2 == 2) ? 0 : sl2 + 1;
    }

    // Epilogue: C/D layout col = lane15 (frag jj), row = quad*4 + r (frag ii)
    float rowb_[4][4];
    if (BIASROW) {
#pragma unroll
        for (int i = 0; i < 4; i++)
#pragma unroll
            for (int r = 0; r < 4; r++)
                rowb_[i][r] = bias0[bm0 + wm * 64 + i * 16 + quad * 4 + r];
    }
    float gsum = 0.0f;
#pragma unroll
    for (int jj = 0; jj < 4; jj++) {
        int col = bn0 + wn * 64 + jj * 16 + lane15;
        int seg, cl, cstride;
        if (NSPLIT == 1) { seg = 0; cl = col; cstride = N; }
        else             { seg = col >> 10; cl = col & 1023; cstride = 1024; }
        const float* bp = (seg == 0) ? bias0 : bias1;
        void* cb = (seg == 0) ? C0 : C1;
        u16*   c16 = (u16*)cb   + (long long)b * sCb;
        float* c32 = (float*)cb + (long long)b * sCb;
        float bvc = (!BIASROW && bp) ? bp[cl] : 0.0f;
        float wgc = GATE ? Wg[cl] : 0.0f;
#pragma unroll
        for (int i = 0; i < 4; i++) {
            int row0 = bm0 + wm * 64 + i * 16 + quad * 4;
#pragma unroll
            for (int r = 0; r < 4; r++) {
                float v = acc[i][jj][r] * scale + (BIASROW ? rowb_[i][r] : bvc);
                if (GATE) gsum += v * wgc;
                if (COUTF32) c32[(long long)(row0 + r) * cstride + cl] = v;
                else         c16[(long long)(row0 + r) * cstride + cl] = f2bf(v);
            }
        }
    }
    if (GATE) {
        // block-reduce gsum, one atomic per block into gatebuf[batch]
#pragma unroll
        for (int o = 32; o > 0; o >>= 1) gsum += __shfl_xor(gsum, o);
        float* red = (float*)lds;           // LDS free after final wgbar
        __syncthreads();
        if ((tid & 63) == 0) red[tid >> 6] = gsum;
        __syncthreads();
        if (tid == 0)
            atomicAdd(&gatebuf[bm0 >> 11],
                      red[0] + red[1] + red[2] + red[3]);
    }
}

// Standalone wrapper with XCD-aware bijective swizzle (grid total % 8 == 0).
template <int COUTF32, int BIASROW, int NSPLIT, int NFAST, int GATE>
__global__ __launch_bounds__(256, 3) void gemm_o(
    const u16* __restrict__ A, const u16* __restrict__ Bt,
    const float* __restrict__ bias0, const float* __restrict__ bias1,
    void* __restrict__ C0, void* __restrict__ C1,
    int M, int N, int K, int ldb, float scale,
    long long sAb, long long sBb, long long sCb, long long bofs_stride,
    const float* __restrict__ Wg, float* __restrict__ gatebuf)
{
    __shared__ u16 lds[24576];   // 48KB: As 3x4096 | Bs 3x4096

    int gx = gridDim.x, gy = gridDim.y;
    int n = gx * gy * gridDim.z;
    int flat = (blockIdx.z * gy + blockIdx.y) * gx + blockIdx.x;
    int L = (flat & 7) * (n >> 3) + (flat >> 3);
    int bz = L / (gx * gy);
    int rr = L - bz * gx * gy;
    int bx, by;
    if (NFAST) { bx = rr / gy; by = rr - bx * gy; }   // N-tile fastest: A hot
    else       { by = rr / gx; bx = rr - by * gx; }   // M-tile fastest: B hot

    gemm_body<COUTF32, BIASROW, NSPLIT, GATE>(
        A, Bt, bias0, bias1, C0, C1, M, N, K, ldb, scale,
        sAb, sBb, sCb, bofs_stride, bx, by, bz, threadIdx.x, Wg, gatebuf, lds);
}

// ---------------------------------------------------------------------------
// Merged independent GEMMs (one dispatch, true overlap):
//   blocks [0,1024):    Q|K proj  C[8192,2048] = xb @ [Wq;Wk]^T (NSPLIT=2)
//   blocks [1024,1536): Vt        C[1024,8192] = Wvb @ xb^T + bv(row)
// 1536 blocks = exactly 2 full rounds of 768 co-resident slots (3/CU).
// ---------------------------------------------------------------------------
__global__ __launch_bounds__(256, 3) void qkv_k(
    const u16* __restrict__ xb, const u16* __restrict__ Wqb,
    const float* __restrict__ bq, const float* __restrict__ bk,
    u16* __restrict__ Q, u16* __restrict__ Kb,
    const u16* __restrict__ Wvb, const float* __restrict__ bv,
    u16* __restrict__ Vt)
{
    __shared__ u16 lds[24576];
    int flat = blockIdx.x;
    int tid = threadIdx.x;
    if (flat < 1024) {
        // internal grid 64(M) x 16(N), NFAST=1 (A panels hot)
        int L = (flat & 7) * 128 + (flat >> 3);
        int bx = L / 16, by = L - bx * 16;
        gemm_body<0, 0, 2, 0>(
            xb, Wqb, bq, bk, Q, Kb, 8192, 2048, 1024, 1024, 1.0f,
            0, 0, 0, 0, bx, by, 0, tid, nullptr, nullptr, lds);
    } else {
        // internal grid 8(M) x 64(N), NFAST=0 (B=xb panels hot)
        int f2 = flat - 1024;
        int L = (f2 & 7) * 64 + (f2 >> 3);
        int by = L / 8, bx = L - by * 8;
        gemm_body<0, 1, 1, 0>(
            Wvb, xb, bv, nullptr, Vt, nullptr, 1024, 8192, 1024, 1024, 1.0f,
            0, 0, 0, 0, bx, by, 0, tid, nullptr, nullptr, lds);
    }
}

// ---------------------------------------------------------------------------
// Row softmax in-place: 8192 rows of 2048 bf16. Block 0 also zeroes the
// 4-float gate accumulator (ordered before PV's atomics).
// ---------------------------------------------------------------------------
__global__ __launch_bounds__(256) void softmax_k(u16* __restrict__ Sc,
                                                 float* __restrict__ gatebuf)
{
    long long row = blockIdx.x;
    u16* s = Sc + row * 2048;
    int t = threadIdx.x;
    if (blockIdx.x == 0 && t < 4) gatebuf[t] = 0.0f;

    uint4 raw = *(const uint4*)(s + t * 8);
    const u16* rp = (const u16*)&raw;
    float v[8];
    float mx = -3.4e38f;
#pragma unroll
    for (int j = 0; j < 8; j++) { v[j] = bf2f(rp[j]); mx = fmaxf(mx, v[j]); }
#pragma unroll
    for (int o = 32; o > 0; o >>= 1) mx = fmaxf(mx, __shfl_xor(mx, o));
    __shared__ float redm[4];
    if ((t & 63) == 0) redm[t >> 6] = mx;
    __syncthreads();
    mx = fmaxf(fmaxf(redm[0], redm[1]), fmaxf(redm[2], redm[3]));

    float sum = 0.0f;
#pragma unroll
    for (int j = 0; j < 8; j++) { v[j] = __expf(v[j] - mx); sum += v[j]; }
#pragma unroll
    for (int o = 32; o > 0; o >>= 1) sum += __shfl_xor(sum, o);
    __shared__ float reds[4];
    if ((t & 63) == 0) reds[t >> 6] = sum;
    __syncthreads();
    sum = reds[0] + reds[1] + reds[2] + reds[3];

    float inv = 1.0f / sum;
    u16 o8[8];
#pragma unroll
    for (int j = 0; j < 8; j++) o8[j] = f2bf(v[j] * inv);
    *(uint4*)(s + t * 8) = *(const uint4*)o8;
}

// ---------------------------------------------------------------------------
// Epilogue: z = relu(mu + eps*exp(0.5*logvar)); out = LN(x+z)*gamma+beta
// Vectorized float4. Block 0 also finishes the gate: sigmoid(part/2048+bg).
// ---------------------------------------------------------------------------
__global__ __launch_bounds__(256) void epilogue_k(
    const float* __restrict__ x, const float* __restrict__ ep,
    const float* __restrict__ mu, const float* __restrict__ lv,
    const float* __restrict__ gamma, const float* __restrict__ beta,
    float* __restrict__ out, const float* __restrict__ bg,
    float* __restrict__ pg)
{
    long long base = (long long)blockIdx.x * 1024;
    int t = threadIdx.x;
    int i0 = t * 4;
    if (blockIdx.x == 0 && t < 4) {
        float v = pg[t] * (1.0f / 2048.0f) + bg[0];
        pg[t] = 1.0f / (1.0f + __expf(-v));
    }

    float4 xv = *(const float4*)&x[base + i0];
    float4 ev = *(const float4*)&ep[base + i0];
    float4 mv = *(const float4*)&mu[base + i0];
    float4 lw = *(const float4*)&lv[base + i0];

    float y[4];
    y[0] = xv.x + fmaxf(mv.x + ev.x * __expf(0.5f * lw.x), 0.0f);
    y[1] = xv.y + fmaxf(mv.y + ev.y * __expf(0.5f * lw.y), 0.0f);
    y[2] = xv.z + fmaxf(mv.z + ev.z * __expf(0.5f * lw.z), 0.0f);
    y[3] = xv.w + fmaxf(mv.w + ev.w * __expf(0.5f * lw.w), 0.0f);

    float sum = 0.0f, sq = 0.0f;
#pragma unroll
    for (int j = 0; j < 4; j++) { sum += y[j]; sq += y[j] * y[j]; }
#pragma unroll
    for (int o = 32; o > 0; o >>= 1) { sum += __shfl_xor(sum, o); sq += __shfl_xor(sq, o); }
    __shared__ float rs[4], rq[4];
    if ((t & 63) == 0) { rs[t >> 6] = sum; rq[t >> 6] = sq; }
    __syncthreads();
    sum = rs[0] + rs[1] + rs[2] + rs[3];
    sq  = rq[0] + rq[1] + rq[2] + rq[3];
    float mean = sum * (1.0f / 1024.0f);
    float var  = fmaxf(sq * (1.0f / 1024.0f) - mean * mean, 0.0f);
    float rstd = rsqrtf(var + 1e-5f);

    float4 gv = *(const float4*)&gamma[i0];
    float4 bv = *(const float4*)&beta[i0];
    float4 o;
    o.x = (y[0] - mean) * rstd * gv.x + bv.x;
    o.y = (y[1] - mean) * rstd * gv.y + bv.y;
    o.z = (y[2] - mean) * rstd * gv.z + bv.z;
    o.w = (y[3] - mean) * rstd * gv.w + bv.w;
    *(float4*)&out[base + i0] = o;
}

// ---------------------------------------------------------------------------
extern "C" void kernel_launch(void* const* d_in, const int* in_sizes, int n_in,
                              void* d_out, int out_size, void* d_ws, size_t ws_size,
                              hipStream_t stream)
{
    const float* x     = (const float*)d_in[0];
    const float* ep    = (const float*)d_in[1];
    const float* Wq    = (const float*)d_in[2];
    const float* bq    = (const float*)d_in[3];
    const float* Wk    = (const float*)d_in[4];
    const float* bk    = (const float*)d_in[5];
    const float* Wv    = (const float*)d_in[6];
    const float* bv    = (const float*)d_in[7];
    const float* Wmu   = (const float*)d_in[8];
    const float* bmu   = (const float*)d_in[9];
    const float* Wlv   = (const float*)d_in[10];
    const float* blv   = (const float*)d_in[11];
    const float* Wg    = (const float*)d_in[12];
    const float* bg    = (const float*)d_in[13];
    const float* gamma = (const float*)d_in[14];
    const float* beta  = (const float*)d_in[15];
    float* out = (float*)d_out;

    const int M = 8192;       // B*S
    const int D = 1024;
    const int S = 2048;

    float* mu_out = out + 8388608LL;
    float* lv_out = out + 16777216LL;
    float* pg_out = out + 25165824LL;

    // Scratch overlays (d_out dead regions; ws = h only):
    //  out region: [0-1] xb | Wqb|Wkb (adjacent) | Wvb
    //              [2-4] Sc (33.55MB, overwrites all of the above)
    //              [5-6] Wmub|Wlvb (adjacent, @+4MB, inside dead Sc)
    //              [7]   final out f32
    //  mu region: Q | Kb -> then mu_out f32
    //  lv region: VtAll [1024][8192] -> then lv_out f32
    //  pg region: gate accumulator (zeroed by softmax, atomics in PV,
    //             sigmoid in epilogue) -> final p_gate
    u16* xb   = (u16*)out;
    u16* Wqb  = (u16*)out + 8388608LL;     // [2048][1024]: Wq then Wk
    u16* Wkb  = (u16*)out + 9437184LL;
    u16* Wvb  = (u16*)out + 10485760LL;
    u16* Sc   = (u16*)out;
    u16* Q    = (u16*)mu_out;
    u16* Kb   = (u16*)mu_out + 8388608LL;
    u16* Vt   = (u16*)lv_out;              // VtAll [1024][8192]
    u16* h    = (u16*)d_ws;
    u16* Wmub = (u16*)out + 2097152LL;     // [2048][1024]: Wmu then Wlv
    u16* Wlvb = (u16*)out + 3145728LL;

    dim3 blk(256);

    // 0. Convert x, Wq, Wk, Wv to bf16.
    cvt_bf16_k<<<dim3(2048, 4), blk, 0, stream>>>(
        x,  xb,  2097152LL,
        Wq, Wqb, 262144LL,
        Wk, Wkb, 262144LL,
        Wv, Wvb, 262144LL);

    // 1. Merged: Q|K proj (1024 blocks) + Vt (512 blocks), one dispatch.
    qkv_k<<<dim3(1536), blk, 0, stream>>>(
        xb, Wqb, bq, bk, Q, Kb, Wvb, bv, Vt);

    // 2. scores = Q @ K^T / 48 per batch -> Sc (xb/W*b now dead)
    gemm_o<0, 0, 1, 1, 0><<<dim3(16, 16, 4), blk, 0, stream>>>(
        Q, Kb, nullptr, nullptr, Sc, nullptr,
        S, S, D, D, 1.0f / 48.0f,
        (long long)S * D, (long long)S * D, (long long)S * S, 0,
        nullptr, nullptr);

    // 3. softmax in place (+ zero gate accumulator)
    softmax_k<<<dim3(8192), blk, 0, stream>>>(Sc, pg_out);

    // 4. h = P @ V (+ fused gate partials): A=Sc, B=VtAll (ldb=8192,
    //    +b*2048 K-offset)
    gemm_o<0, 0, 1, 1, 1><<<dim3(64, 8, 1), blk, 0, stream>>>(
        Sc, Vt, nullptr, nullptr, h, nullptr,
        M, D, S, 8192, 1.0f, 0, 0, 0, 2048,
        Wg, pg_out);

    // 5. Convert Wmu, Wlv into dead Sc region (adjacent [2048][1024]).
    cvt_bf16_k<<<dim3(512, 2), blk, 0, stream>>>(
        Wmu, Wmub, 262144LL,
        Wlv, Wlvb, 262144LL,
        nullptr, nullptr, 0LL,
        nullptr, nullptr, 0LL);

    // 6. mu|lv fused: C[8192,2048] = h @ [Wmu;Wlv]^T, split -> mu_out, lv_out
    gemm_o<1, 0, 2, 1, 0><<<dim3(64, 16, 1), blk, 0, stream>>>(
        h, Wmub, bmu, blv, (void*)mu_out, (void*)lv_out,
        M, 2048, D, D, 1.0f, 0, 0, 0, 0,
        nullptr, nullptr);

    // 7. out = LN(x + relu(mu + eps*exp(0.5*logvar))) (+ gate sigmoid)
    epilogue_k<<<dim3(8192), blk, 0, stream>>>(
        x, ep, mu_out, lv_out, gamma, beta, out, bg, pg_out);
}